// Round 1
// 557.106 us; speedup vs baseline: 1.0504x; 1.0504x over previous
//
#include <hip/hip_runtime.h>

// ---------------------------------------------------------------------------
// Whitening2d: B=32, S=2048, F=512, fp32 in/out.
// Uncentered-Gram + commuting-polynomial Newton-Schulz:
//   trace precomputed from colwise sum-of-squares (K1/K2) -> scal[b]
//   G = x^T x;  sigma = 0.9 rcov + 0.1 ((G - rank1corr)/2047 + eps I)
//     (MODE 0 epilogue also emits S16 = bf16(sigma/tr) directly)
//   P1 = 1.5I - 0.5 sn (exact); W = sn^2 GEMM with fused T/U epilogue (MODE 6):
//     T = 2.25I -1.5 sn +0.25 W ; U = 1.5 sn -0.5 W
//   P2 = 1.5 P1 - 0.5 T*U (MODE 4)
//   iter 3: dual {T=P^2,U=P*sn}; P3 = 1.5P - 0.5 T*U (MODE 2, keeps P32)
//   iter 4: dual; P4 = 1.5P - 0.5 T*U (MODE 7, bf16 only - P32 dead after)
//   out = (x@P4 - mv@P4) * tr^{-1/2}
// ---------------------------------------------------------------------------

#define Bb 32
#define Ss 2048
#define Ff 512

typedef __attribute__((ext_vector_type(8))) short bf16x8;
typedef __attribute__((ext_vector_type(4))) float f32x4;

__device__ __forceinline__ unsigned short f2bf(float f) {
    unsigned int u = __float_as_uint(f);
    u += 0x7fffu + ((u >> 16) & 1u);   // RTNE
    return (unsigned short)(u >> 16);
}
__device__ __forceinline__ float bf2f(unsigned short u) {
    return __uint_as_float(((unsigned int)u) << 16);
}
__device__ __forceinline__ ushort4 f4bf(float4 v) {
    ushort4 h;
    h.x = f2bf(v.x); h.y = f2bf(v.y); h.z = f2bf(v.z); h.w = f2bf(v.w);
    return h;
}

__device__ __forceinline__ void gload_lds16(const void* g, void* l) {
    __builtin_amdgcn_global_load_lds(
        (const __attribute__((address_space(1))) void*)g,
        (__attribute__((address_space(3))) void*)l,
        16, 0, 0);
}

// ---------------------------------------------------------------------------
// K1: one pass over x: x16 (bf16), xT16 (bf16 transpose via LDS), col-sums,
// col-sums-of-squares (for trace precompute).
// grid (32, 8, 32), block 256. All LDS scalar ops <=2-way bank alias (free).
__global__ __launch_bounds__(256) void cast_transpose(
    const float* __restrict__ x, unsigned short* __restrict__ x16,
    unsigned short* __restrict__ xT16, float* __restrict__ msum_p,
    float* __restrict__ msumsq_p) {
    __shared__ float tT[64][65];     // [f][s], pad 65: scalar r/w conflict-free
    __shared__ float psum[16][64];
    __shared__ float psumq[16][64];
    int b = blockIdx.z;
    int s0 = blockIdx.x * 64;
    int f0 = blockIdx.y * 64;
    int t = threadIdx.x;
    int fg = t & 15, sr = t >> 4;    // fg: f-chunk 0..15, sr: 0..15
    const float* px = x + ((long)b * Ss + s0) * Ff + f0;
    unsigned short* p16 = x16 + ((long)b * Ss + s0) * Ff + f0;
    float sm0 = 0.f, sm1 = 0.f, sm2 = 0.f, sm3 = 0.f;
    float sq0 = 0.f, sq1 = 0.f, sq2 = 0.f, sq3 = 0.f;
#pragma unroll
    for (int r = 0; r < 4; ++r) {
        int s = r * 16 + sr;
        float4 v = *reinterpret_cast<const float4*>(px + (long)s * Ff + fg * 4);
        *reinterpret_cast<ushort4*>(p16 + (long)s * Ff + fg * 4) = f4bf(v);
        tT[fg * 4 + 0][s] = v.x;
        tT[fg * 4 + 1][s] = v.y;
        tT[fg * 4 + 2][s] = v.z;
        tT[fg * 4 + 3][s] = v.w;
        sm0 += v.x; sm1 += v.y; sm2 += v.z; sm3 += v.w;
        sq0 += v.x * v.x; sq1 += v.y * v.y;
        sq2 += v.z * v.z; sq3 += v.w * v.w;
    }
    *reinterpret_cast<float4*>(&psum[sr][fg * 4]) = make_float4(sm0, sm1, sm2, sm3);
    *reinterpret_cast<float4*>(&psumq[sr][fg * 4]) = make_float4(sq0, sq1, sq2, sq3);
    __syncthreads();
    if (t < 64) {
        float a = 0.f, aq = 0.f;
#pragma unroll
        for (int i = 0; i < 16; ++i) { a += psum[i][t]; aq += psumq[i][t]; }
        msum_p[((long)b * 32 + blockIdx.x) * Ff + f0 + t] = a;
        msumsq_p[((long)b * 32 + blockIdx.x) * Ff + f0 + t] = aq;
    }
    // phase 2: transposed store, rows of tT -> 8B/lane
    int sg = t & 15, fr0 = t >> 4;
    unsigned short* pT = xT16 + ((long)b * Ff + f0) * Ss + s0;
#pragma unroll
    for (int r = 0; r < 4; ++r) {
        int f = r * 16 + fr0;
        float4 v = make_float4(tT[f][sg * 4], tT[f][sg * 4 + 1],
                               tT[f][sg * 4 + 2], tT[f][sg * 4 + 3]);
        *reinterpret_cast<ushort4*>(pT + (long)f * Ss + sg * 4) = f4bf(v);
    }
}

// ---------------------------------------------------------------------------
// K2: reduce col-sum partials -> mbar (batch mean), mv (blended mean),
// and precompute trace(sigma) -> scal[b]:
//   tr = sum_f [0.9*rcov_ff + 0.1*((G_ff - corr_ff)/2047 + eps)]
//   G_ff = colwise sum of squares; corr_ff = 2048*(2*bm_f*mv_f - mv_f^2)
__global__ __launch_bounds__(256) void meanred(
    const float* __restrict__ msum_p, const float* __restrict__ msumsq_p,
    const float* __restrict__ rm, const float* __restrict__ rcov,
    float* __restrict__ mbar, float* __restrict__ mv,
    float* __restrict__ scal) {
    int b = blockIdx.x, t = threadIdx.x;
    float tp = 0.f;
#pragma unroll
    for (int h = 0; h < 2; ++h) {
        int f = t + h * 256;
        float s = 0.f, q = 0.f;
#pragma unroll 8
        for (int st = 0; st < 32; ++st) {
            s += msum_p[((long)b * 32 + st) * Ff + f];
            q += msumsq_p[((long)b * 32 + st) * Ff + f];
        }
        float mb_ = s * (1.0f / 2048.0f);
        float mvv = 0.9f * rm[f] + 0.1f * mb_;
        mbar[b * Ff + f] = mb_;
        mv[b * Ff + f] = mvv;
        float corr = 2048.0f * (2.0f * mb_ * mvv - mvv * mvv);
        float rc = rcov[(long)f * Ff + f];
        tp += 0.9f * rc + 0.1f * ((q - corr) * (1.0f / 2047.0f) + 1e-5f);
    }
    __shared__ float red[4];
#pragma unroll
    for (int off = 32; off; off >>= 1) tp += __shfl_down(tp, off, 64);
    if ((t & 63) == 0) red[t >> 6] = tp;
    __syncthreads();
    if (t == 0) scal[b] = (red[0] + red[1]) + (red[2] + red[3]);
}

// ---------------------------------------------------------------------------
// K3: BT-form GEMM.  C[m][n] = sum_k A[m][k] * Bt[n][k].
// 1D grid, XCD batch clustering (lin&7 = XCD, 4 batches/XCD).
// MODE 0: sigma epilogue -> out32 (sig) + out16 = bf16(sig/tr)
// MODE 1: out16 = bf16(C)                 (DUAL: half grid uses A2/B2/out16b)
// MODE 2: P' = 1.5*out32 - 0.5C -> out32 (rw), out16
// MODE 3: out = (C - vvec[n]) * rsqrt(tr) -> out32
// MODE 4: p1 = 1.5I - 0.5*aux32/tr; P'=1.5p1-0.5C -> out32, out16
// MODE 6: W-epilogue: sn=aux32/tr; out16 = bf16(2.25I-1.5sn+0.25C),
//         out16b = bf16(1.5sn-0.5C)
// MODE 7: P' = 1.5*aux32 - 0.5C -> out16 only (final NS iter, P32 dead)
#define BK 32

template <int MODE, int BM, int BN, int MT, int NT, bool DUAL>
__global__ __launch_bounds__(256, (BN == 64 ? 4 : 3)) void gemm_bt(
    const unsigned short* __restrict__ A, int lda, long strideA,
    const unsigned short* __restrict__ Bt, int ldb, long strideB,
    const unsigned short* __restrict__ A2, const unsigned short* __restrict__ B2,
    int K,
    const float* __restrict__ aux32,
    float* __restrict__ out32,
    unsigned short* __restrict__ out16,
    unsigned short* __restrict__ out16b,
    const float* __restrict__ mbar,
    const float* __restrict__ mv,
    const float* __restrict__ vvec,
    float* __restrict__ scal,
    int ldc, long strideC) {
    constexpr int AR = BM / 64, BR = BN / 64;
    constexpr int WM = BM / 2, WN = BN / 2;
    constexpr int MI = WM / 16, NJ = WN / 16;
    constexpr int NTILES = MT * NT;
    constexpr int TB = (NTILES == 16) ? 4 : ((NTILES == 32) ? 5 : 6);
    __shared__ unsigned short sA[BM * BK];
    __shared__ unsigned short sB[BN * BK];

    int lin = blockIdx.x;
    bool sel = false;
    if constexpr (DUAL) {
        int half = gridDim.x >> 1;
        sel = lin >= half;
        if (sel) lin -= half;
    }
    int b = (lin & 7) * 4 + (lin >> (3 + TB));
    int tile = (lin >> 3) & (NTILES - 1);
    int m0 = (tile & (MT - 1)) * BM;
    int n0 = (tile / MT) * BN;

    int t = threadIdx.x;
    int w = t >> 6, l = t & 63;
    int wm = (w >> 1) * WM, wn = (w & 1) * WN;

    const unsigned short* Ap = (DUAL && sel) ? A2 : A;
    const unsigned short* Bp = (DUAL && sel) ? B2 : Bt;
    unsigned short* o16 = (DUAL && sel) ? out16b : out16;

    const unsigned short* gA = Ap + (long)b * strideA;
    const unsigned short* gB = Bp + (long)b * strideB;

    int srow = t >> 2, sk = (t & 3) * 8;
    const unsigned short* pa[AR];
    const unsigned short* pb[BR];
#pragma unroll
    for (int r = 0; r < AR; ++r) pa[r] = gA + (long)(m0 + r * 64 + srow) * lda + sk;
#pragma unroll
    for (int r = 0; r < BR; ++r) pb[r] = gB + (long)(n0 + r * 64 + srow) * ldb + sk;
    unsigned short* la = &sA[srow * BK + sk];
    unsigned short* lb = &sB[srow * BK + sk];

    f32x4 acc[MI][NJ] = {};
    int q = l >> 4, r16 = l & 15;
    const unsigned short* fa = &sA[(wm + r16) * BK + q * 8];
    const unsigned short* fb = &sB[(wn + r16) * BK + q * 8];

    for (int k0 = 0; k0 < K; k0 += BK) {
#pragma unroll
        for (int r = 0; r < AR; ++r) { gload_lds16(pa[r], la + r * 64 * BK); pa[r] += BK; }
#pragma unroll
        for (int r = 0; r < BR; ++r) { gload_lds16(pb[r], lb + r * 64 * BK); pb[r] += BK; }
        __syncthreads();
        bf16x8 af[MI], bf[NJ];
#pragma unroll
        for (int i = 0; i < MI; ++i)
            af[i] = *reinterpret_cast<const bf16x8*>(fa + i * 16 * BK);
#pragma unroll
        for (int j = 0; j < NJ; ++j)
            bf[j] = *reinterpret_cast<const bf16x8*>(fb + j * 16 * BK);
#pragma unroll
        for (int i = 0; i < MI; ++i)
#pragma unroll
            for (int j = 0; j < NJ; ++j)
                acc[i][j] = __builtin_amdgcn_mfma_f32_16x16x32_bf16(
                    af[i], bf[j], acc[i][j], 0, 0, 0);
        __syncthreads();
    }

    // epilogue: C[row = wm+i*16+q*4+r][col = wn+j*16+r16]
    int mb = m0 + wm + q * 4;
    int nb = n0 + wn + r16;
    long bF = (long)b * Ff;
    float rs = 0.f, invtr = 0.f;
    if constexpr (MODE == 3) rs = 1.0f / sqrtf(scal[b]);
    if constexpr (MODE == 0 || MODE == 4 || MODE == 6) invtr = 1.0f / scal[b];
#pragma unroll
    for (int i = 0; i < MI; ++i) {
#pragma unroll
        for (int j = 0; j < NJ; ++j) {
#pragma unroll
            for (int r = 0; r < 4; ++r) {
                int m = mb + i * 16 + r;
                int n = nb + j * 16;
                long idx = (long)b * strideC + (long)m * ldc + n;
                float v = acc[i][j][r];
                if constexpr (MODE == 0) {
                    float bm_m = mbar[bF + m], bm_n = mbar[bF + n];
                    float mv_m = mv[bF + m], mv_n = mv[bF + n];
                    float corr = 2048.0f * (bm_m * mv_n + mv_m * bm_n - mv_m * mv_n);
                    float rc = aux32[(long)m * ldc + n];
                    float d = (m == n) ? 1e-5f : 0.0f;
                    float sig = 0.9f * rc + 0.1f * ((v - corr) * (1.0f / 2047.0f) + d);
                    out32[idx] = sig;
                    out16[idx] = f2bf(sig * invtr);
                } else if constexpr (MODE == 1) {
                    o16[idx] = f2bf(v);
                } else if constexpr (MODE == 2) {
                    float pn = 1.5f * out32[idx] - 0.5f * v;
                    out32[idx] = pn;
                    out16[idx] = f2bf(pn);
                } else if constexpr (MODE == 3) {
                    out32[idx] = (v - vvec[bF + n]) * rs;
                } else if constexpr (MODE == 4) {
                    float p1 = ((m == n) ? 1.5f : 0.0f) - 0.5f * aux32[idx] * invtr;
                    float pn = 1.5f * p1 - 0.5f * v;
                    out32[idx] = pn;
                    out16[idx] = f2bf(pn);
                } else if constexpr (MODE == 6) {
                    float sn = aux32[idx] * invtr;
                    float dt = (m == n) ? 2.25f : 0.0f;
                    out16[idx]  = f2bf(dt - 1.5f * sn + 0.25f * v);
                    out16b[idx] = f2bf(1.5f * sn - 0.5f * v);
                } else if constexpr (MODE == 7) {
                    out16[idx] = f2bf(1.5f * aux32[idx] - 0.5f * v);
                } else {
                    out32[idx] = v;
                }
            }
        }
    }
}

// ---------------------------------------------------------------------------
// K6: vvec[b][n] = sum_k mv[b][k] * P16[b][k][n]
__global__ __launch_bounds__(256) void mvecp(
    const float* __restrict__ mv, const unsigned short* __restrict__ P16,
    float* __restrict__ vvec) {
    int b = blockIdx.x;
    int n = blockIdx.y * 256 + threadIdx.x;
    const unsigned short* P = P16 + (long)b * Ff * Ff + n;
    const float* m = mv + (long)b * Ff;
    float a0 = 0.f, a1 = 0.f, a2 = 0.f, a3 = 0.f;
    for (int k = 0; k < Ff; k += 4) {
        a0 += m[k]     * bf2f(P[(long)k * Ff]);
        a1 += m[k + 1] * bf2f(P[(long)(k + 1) * Ff]);
        a2 += m[k + 2] * bf2f(P[(long)(k + 2) * Ff]);
        a3 += m[k + 3] * bf2f(P[(long)(k + 3) * Ff]);
    }
    vvec[(long)b * Ff + n] = (a0 + a1) + (a2 + a3);
}

// ---------------------------------------------------------------------------
extern "C" void kernel_launch(void* const* d_in, const int* in_sizes, int n_in,
                              void* d_out, int out_size, void* d_ws, size_t ws_size,
                              hipStream_t stream) {
    const float* x    = (const float*)d_in[0];
    const float* rm   = (const float*)d_in[1];
    const float* rcov = (const float*)d_in[2];
    float* out = (float*)d_out;

    char* ws = (char*)d_ws;
    unsigned short* x16   = (unsigned short*)(ws);                 // 64 MB
    unsigned short* xT16  = (unsigned short*)(ws + 67108864L);     // 64 MB
    float*          sig32 = (float*)(ws + 134217728L);             // 32 MB
    float*          P32   = (float*)(ws + 167772160L);             // 32 MB
    unsigned short* S16   = (unsigned short*)(ws + 201326592L);    // 16 MB
    unsigned short* P16   = (unsigned short*)(ws + 218103808L);    // 16 MB
    unsigned short* T16   = (unsigned short*)(ws + 234881024L);    // 16 MB
    unsigned short* U16   = (unsigned short*)(ws + 251658240L);    // 16 MB
    float*          msum_p= (float*)(ws + 268435456L);             // 2 MB
    float*          mbar  = (float*)(ws + 270532608L);             // 64 KB
    float*          mv    = (float*)(ws + 270598144L);             // 64 KB
    float*          vvec  = (float*)(ws + 270663680L);             // 64 KB
    float*          scal  = (float*)(ws + 270729216L);             // 128 B
    float*          msumsq_p = (float*)d_out;  // 2 MB scratch, overwritten by final

    const long sFF = (long)Ff * Ff;
    const long sSF = (long)Ss * Ff;

    cast_transpose<<<dim3(Ss / 64, Ff / 64, Bb), 256, 0, stream>>>(
        x, x16, xT16, msum_p, msumsq_p);
    meanred<<<Bb, 256, 0, stream>>>(msum_p, msumsq_p, rm, rcov, mbar, mv, scal);

    // sigma (fp32) + S16 = bf16(sigma/tr) fused (trace already in scal)
    gemm_bt<0, 128, 128, 4, 4, false><<<512, 256, 0, stream>>>(
        xT16, Ss, sSF, xT16, Ss, sSF, nullptr, nullptr, Ss,
        rcov, sig32, S16, nullptr, mbar, mv, nullptr, scal, Ff, sFF);

    // G1: W = sn^2, fused T/U epilogue (T = P1^2, U = P1*sn)
    gemm_bt<6, 128, 64, 4, 8, false><<<1024, 256, 0, stream>>>(
        S16, Ff, sFF, S16, Ff, sFF, nullptr, nullptr, Ff,
        sig32, nullptr, T16, U16, nullptr, nullptr, nullptr, scal, Ff, sFF);
    // G2: P2 = 1.5 P1 - 0.5 T*U   (P1 from sigma inline)
    gemm_bt<4, 128, 64, 4, 8, false><<<1024, 256, 0, stream>>>(
        T16, Ff, sFF, U16, Ff, sFF, nullptr, nullptr, Ff,
        sig32, P32, P16, nullptr, nullptr, nullptr, nullptr, scal, Ff, sFF);

    // iter 3: dual {T=P^2, U=P*sn} then P3 = 1.5P - 0.5 T*U (keeps P32)
    gemm_bt<1, 128, 64, 4, 8, true><<<2048, 256, 0, stream>>>(
        P16, Ff, sFF, P16, Ff, sFF, P16, S16, Ff,
        nullptr, nullptr, T16, U16, nullptr, nullptr, nullptr, nullptr, Ff, sFF);
    gemm_bt<2, 128, 64, 4, 8, false><<<1024, 256, 0, stream>>>(
        T16, Ff, sFF, U16, Ff, sFF, nullptr, nullptr, Ff,
        nullptr, P32, P16, nullptr, nullptr, nullptr, nullptr, nullptr, Ff, sFF);
    // iter 4: dual, then P4 = 1.5P - 0.5 T*U, bf16 output only
    gemm_bt<1, 128, 64, 4, 8, true><<<2048, 256, 0, stream>>>(
        P16, Ff, sFF, P16, Ff, sFF, P16, S16, Ff,
        nullptr, nullptr, T16, U16, nullptr, nullptr, nullptr, nullptr, Ff, sFF);
    gemm_bt<7, 128, 64, 4, 8, false><<<1024, 256, 0, stream>>>(
        T16, Ff, sFF, U16, Ff, sFF, nullptr, nullptr, Ff,
        P32, nullptr, P16, nullptr, nullptr, nullptr, nullptr, nullptr, Ff, sFF);

    mvecp<<<dim3(Bb, 2), 256, 0, stream>>>(mv, P16, vvec);

    // out = (x@P4 - mv@P4) * tr^{-1/2}
    gemm_bt<3, 128, 128, 16, 4, false><<<2048, 256, 0, stream>>>(
        x16, Ff, sSF, P16, Ff, sFF, nullptr, nullptr, Ff,
        nullptr, out, nullptr, nullptr, nullptr, nullptr, vvec, scal, Ff, sSF);
}

// Round 2
// 538.612 us; speedup vs baseline: 1.0865x; 1.0343x over previous
//
#include <hip/hip_runtime.h>

// ---------------------------------------------------------------------------
// Whitening2d: B=32, S=2048, F=512, fp32 in/out.
// Uncentered-Gram + commuting-polynomial Newton-Schulz:
//   trace precomputed from colwise sum-of-squares (K1/K2) -> scal[b]
//   G = x^T x;  sigma = 0.9 rcov + 0.1 ((G - rank1corr)/2047 + eps I)
//     (MODE 0 epilogue also emits S16 = bf16(sigma/tr) directly)
//   P1 = 1.5I - 0.5 sn (exact); W = sn^2 GEMM with fused T/U epilogue (MODE 6):
//     T = 2.25I -1.5 sn +0.25 W ; U = 1.5 sn -0.5 W
//   P2 = 1.5 P1 - 0.5 T*U (MODE 4)
//   iter 3: fused dual {T=P^2,U=P*sn} (MODE 8); P3 = 1.5P - 0.5 T*U (MODE 2)
//   iter 4: fused dual; P4 = 1.5P - 0.5 T*U (MODE 7, bf16 only - P32 dead)
//   out = (x@P4 - mv@P4) * tr^{-1/2}
// ---------------------------------------------------------------------------

#define Bb 32
#define Ss 2048
#define Ff 512

typedef __attribute__((ext_vector_type(8))) short bf16x8;
typedef __attribute__((ext_vector_type(4))) float f32x4;

__device__ __forceinline__ unsigned short f2bf(float f) {
    unsigned int u = __float_as_uint(f);
    u += 0x7fffu + ((u >> 16) & 1u);   // RTNE
    return (unsigned short)(u >> 16);
}
__device__ __forceinline__ float bf2f(unsigned short u) {
    return __uint_as_float(((unsigned int)u) << 16);
}
__device__ __forceinline__ ushort4 f4bf(float4 v) {
    ushort4 h;
    h.x = f2bf(v.x); h.y = f2bf(v.y); h.z = f2bf(v.z); h.w = f2bf(v.w);
    return h;
}

__device__ __forceinline__ void gload_lds16(const void* g, void* l) {
    __builtin_amdgcn_global_load_lds(
        (const __attribute__((address_space(1))) void*)g,
        (__attribute__((address_space(3))) void*)l,
        16, 0, 0);
}

// ---------------------------------------------------------------------------
// K1: one pass over x: x16 (bf16), xT16 (bf16 transpose via LDS), col-sums,
// col-sums-of-squares (for trace precompute).
// bf16 LDS transpose tile (convert once), XOR-swizzled columns:
//   element (f, s) stored at col = s ^ ((f>>2)<<2)  -> phase-1 scalar writes
//   hit 64 distinct ushort offsets mod 64 per instr (2-way same-word = free);
//   phase-2 ushort4 reads stay contiguous (swizzle only touches bits 2-5).
// Partial sums: wave shfl_xor reduce (sub-rows 16/32) + 2KB LDS cross-wave.
// LDS total 10.25 KB (was 25 KB) -> occupancy cap 8 blocks/CU.
__global__ __launch_bounds__(256) void cast_transpose(
    const float* __restrict__ x, unsigned short* __restrict__ x16,
    unsigned short* __restrict__ xT16, float* __restrict__ msum_p,
    float* __restrict__ msumsq_p) {
    __shared__ unsigned short tT[64 * 64];   // swizzled transposed bf16 tile
    __shared__ float red[4][2][64];          // per-wave reduced sums / sqsums
    int b = blockIdx.z;
    int s0 = blockIdx.x * 64;
    int f0 = blockIdx.y * 64;
    int t = threadIdx.x;
    int fg = t & 15, sr = t >> 4;    // fg: f-chunk 0..15, sr: 0..15
    const float* px = x + ((long)b * Ss + s0) * Ff + f0;
    unsigned short* p16 = x16 + ((long)b * Ss + s0) * Ff + f0;
    float sm0 = 0.f, sm1 = 0.f, sm2 = 0.f, sm3 = 0.f;
    float sq0 = 0.f, sq1 = 0.f, sq2 = 0.f, sq3 = 0.f;
    int swz = fg << 2;               // f>>2 == fg for all 4 components
#pragma unroll
    for (int r = 0; r < 4; ++r) {
        int s = r * 16 + sr;
        float4 v = *reinterpret_cast<const float4*>(px + (long)s * Ff + fg * 4);
        ushort4 h = f4bf(v);
        *reinterpret_cast<ushort4*>(p16 + (long)s * Ff + fg * 4) = h;
        int c = s ^ swz;
        tT[(fg * 4 + 0) * 64 + c] = h.x;
        tT[(fg * 4 + 1) * 64 + c] = h.y;
        tT[(fg * 4 + 2) * 64 + c] = h.z;
        tT[(fg * 4 + 3) * 64 + c] = h.w;
        sm0 += v.x; sm1 += v.y; sm2 += v.z; sm3 += v.w;
        sq0 += v.x * v.x; sq1 += v.y * v.y;
        sq2 += v.z * v.z; sq3 += v.w * v.w;
    }
    // wave-level reduce over the wave's 4 sub-rows (lanes l, l^16, l^32, l^48)
    sm0 += __shfl_xor(sm0, 16); sm1 += __shfl_xor(sm1, 16);
    sm2 += __shfl_xor(sm2, 16); sm3 += __shfl_xor(sm3, 16);
    sq0 += __shfl_xor(sq0, 16); sq1 += __shfl_xor(sq1, 16);
    sq2 += __shfl_xor(sq2, 16); sq3 += __shfl_xor(sq3, 16);
    sm0 += __shfl_xor(sm0, 32); sm1 += __shfl_xor(sm1, 32);
    sm2 += __shfl_xor(sm2, 32); sm3 += __shfl_xor(sm3, 32);
    sq0 += __shfl_xor(sq0, 32); sq1 += __shfl_xor(sq1, 32);
    sq2 += __shfl_xor(sq2, 32); sq3 += __shfl_xor(sq3, 32);
    int w = t >> 6, l = t & 63;
    if (l < 16) {
        *reinterpret_cast<float4*>(&red[w][0][l * 4]) =
            make_float4(sm0, sm1, sm2, sm3);
        *reinterpret_cast<float4*>(&red[w][1][l * 4]) =
            make_float4(sq0, sq1, sq2, sq3);
    }
    __syncthreads();
    if (t < 64) {
        float a = (red[0][0][t] + red[1][0][t]) + (red[2][0][t] + red[3][0][t]);
        float aq = (red[0][1][t] + red[1][1][t]) + (red[2][1][t] + red[3][1][t]);
        msum_p[((long)b * 32 + blockIdx.x) * Ff + f0 + t] = a;
        msumsq_p[((long)b * 32 + blockIdx.x) * Ff + f0 + t] = aq;
    }
    // phase 2: transposed store, ushort4 reads from swizzled tile
    int sg = t & 15, fr0 = t >> 4;
    unsigned short* pT = xT16 + ((long)b * Ff + f0) * Ss + s0;
#pragma unroll
    for (int r = 0; r < 4; ++r) {
        int f = r * 16 + fr0;
        int c0 = (sg * 4) ^ (((f >> 2) & 15) << 2);
        ushort4 hv = *reinterpret_cast<const ushort4*>(&tT[f * 64 + c0]);
        *reinterpret_cast<ushort4*>(pT + (long)f * Ss + sg * 4) = hv;
    }
}

// ---------------------------------------------------------------------------
// K2: reduce col-sum partials -> mbar (batch mean), mv (blended mean),
// and precompute trace(sigma) -> scal[b]:
//   tr = sum_f [0.9*rcov_ff + 0.1*((G_ff - corr_ff)/2047 + eps)]
//   G_ff = colwise sum of squares; corr_ff = 2048*(2*bm_f*mv_f - mv_f^2)
__global__ __launch_bounds__(256) void meanred(
    const float* __restrict__ msum_p, const float* __restrict__ msumsq_p,
    const float* __restrict__ rm, const float* __restrict__ rcov,
    float* __restrict__ mbar, float* __restrict__ mv,
    float* __restrict__ scal) {
    int b = blockIdx.x, t = threadIdx.x;
    float tp = 0.f;
#pragma unroll
    for (int h = 0; h < 2; ++h) {
        int f = t + h * 256;
        float s = 0.f, q = 0.f;
#pragma unroll 8
        for (int st = 0; st < 32; ++st) {
            s += msum_p[((long)b * 32 + st) * Ff + f];
            q += msumsq_p[((long)b * 32 + st) * Ff + f];
        }
        float mb_ = s * (1.0f / 2048.0f);
        float mvv = 0.9f * rm[f] + 0.1f * mb_;
        mbar[b * Ff + f] = mb_;
        mv[b * Ff + f] = mvv;
        float corr = 2048.0f * (2.0f * mb_ * mvv - mvv * mvv);
        float rc = rcov[(long)f * Ff + f];
        tp += 0.9f * rc + 0.1f * ((q - corr) * (1.0f / 2047.0f) + 1e-5f);
    }
    __shared__ float red[4];
#pragma unroll
    for (int off = 32; off; off >>= 1) tp += __shfl_down(tp, off, 64);
    if ((t & 63) == 0) red[t >> 6] = tp;
    __syncthreads();
    if (t == 0) scal[b] = (red[0] + red[1]) + (red[2] + red[3]);
}

// ---------------------------------------------------------------------------
// K3: BT-form GEMM.  C[m][n] = sum_k A[m][k] * Bt[n][k].
// 1D grid, XCD batch clustering (lin&7 = XCD, 4 batches/XCD).
// MODE 0: sigma epilogue -> out32 (sig) + out16 = bf16(sig/tr)
// MODE 2: P' = 1.5*out32 - 0.5C -> out32 (rw), out16
// MODE 3: out = (C - vvec[n]) * rsqrt(tr) -> out32
// MODE 4: p1 = 1.5I - 0.5*aux32/tr; P'=1.5p1-0.5C -> out32, out16
// MODE 6: W-epilogue: sn=aux32/tr; out16 = bf16(2.25I-1.5sn+0.25C),
//         out16b = bf16(1.5sn-0.5C)
// MODE 7: P' = 1.5*aux32 - 0.5C -> out16 only (final NS iter, P32 dead)
// MODE 8: fused dual: shared A-panel, two B-panels (Bt, B2):
//         out16 = bf16(A*Bt^T), out16b = bf16(A*B2^T)   [T=P^2, U=P*sn]
#define BK 32

template <int MODE, int BM, int BN, int MT, int NT>
__global__ __launch_bounds__(256, (MODE == 8 ? 3 : (BM * BN <= 8192 ? 4 : 3)))
void gemm_bt(
    const unsigned short* __restrict__ A, int lda, long strideA,
    const unsigned short* __restrict__ Bt, int ldb, long strideB,
    const unsigned short* __restrict__ B2, int K,
    const float* __restrict__ aux32,
    float* __restrict__ out32,
    unsigned short* __restrict__ out16,
    unsigned short* __restrict__ out16b,
    const float* __restrict__ mbar,
    const float* __restrict__ mv,
    const float* __restrict__ vvec,
    float* __restrict__ scal,
    int ldc, long strideC) {
    constexpr bool FUSE = (MODE == 8);
    constexpr int AR = BM / 64, BR = BN / 64;
    constexpr int WM = BM / 2, WN = BN / 2;
    constexpr int MI = WM / 16, NJ = WN / 16;
    constexpr int NTILES = MT * NT;
    constexpr int TB = (NTILES == 16) ? 4 : ((NTILES == 32) ? 5 : 6);
    __shared__ unsigned short sA[BM * BK];
    __shared__ unsigned short sB[BN * BK];
    __shared__ unsigned short sB2[FUSE ? BN * BK : 4];

    int lin = blockIdx.x;
    int b = (lin & 7) * 4 + (lin >> (3 + TB));
    int tile = (lin >> 3) & (NTILES - 1);
    int m0 = (tile & (MT - 1)) * BM;
    int n0 = (tile / MT) * BN;

    int t = threadIdx.x;
    int w = t >> 6, l = t & 63;
    int wm = (w >> 1) * WM, wn = (w & 1) * WN;

    const unsigned short* gA = A + (long)b * strideA;
    const unsigned short* gB = Bt + (long)b * strideB;

    int srow = t >> 2, sk = (t & 3) * 8;
    const unsigned short* pa[AR];
    const unsigned short* pb[BR];
    const unsigned short* pb2[FUSE ? BR : 1];
#pragma unroll
    for (int r = 0; r < AR; ++r) pa[r] = gA + (long)(m0 + r * 64 + srow) * lda + sk;
#pragma unroll
    for (int r = 0; r < BR; ++r) pb[r] = gB + (long)(n0 + r * 64 + srow) * ldb + sk;
    if constexpr (FUSE) {
        const unsigned short* g2 = B2 + (long)b * strideB;
#pragma unroll
        for (int r = 0; r < BR; ++r)
            pb2[r] = g2 + (long)(n0 + r * 64 + srow) * ldb + sk;
    }
    unsigned short* la = &sA[srow * BK + sk];
    unsigned short* lb = &sB[srow * BK + sk];
    unsigned short* lb2 = &sB2[FUSE ? (srow * BK + sk) : 0];

    f32x4 acc[MI][NJ] = {};
    f32x4 acc2[FUSE ? MI : 1][FUSE ? NJ : 1] = {};
    int q = l >> 4, r16 = l & 15;
    const unsigned short* fa = &sA[(wm + r16) * BK + q * 8];
    const unsigned short* fb = &sB[(wn + r16) * BK + q * 8];
    const unsigned short* fb2 = &sB2[FUSE ? ((wn + r16) * BK + q * 8) : 0];

    for (int k0 = 0; k0 < K; k0 += BK) {
#pragma unroll
        for (int r = 0; r < AR; ++r) { gload_lds16(pa[r], la + r * 64 * BK); pa[r] += BK; }
#pragma unroll
        for (int r = 0; r < BR; ++r) { gload_lds16(pb[r], lb + r * 64 * BK); pb[r] += BK; }
        if constexpr (FUSE) {
#pragma unroll
            for (int r = 0; r < BR; ++r) { gload_lds16(pb2[r], lb2 + r * 64 * BK); pb2[r] += BK; }
        }
        __syncthreads();
        bf16x8 af[MI], bf[NJ];
#pragma unroll
        for (int i = 0; i < MI; ++i)
            af[i] = *reinterpret_cast<const bf16x8*>(fa + i * 16 * BK);
#pragma unroll
        for (int j = 0; j < NJ; ++j)
            bf[j] = *reinterpret_cast<const bf16x8*>(fb + j * 16 * BK);
        if constexpr (FUSE) {
            bf16x8 bg[NJ];
#pragma unroll
            for (int j = 0; j < NJ; ++j)
                bg[j] = *reinterpret_cast<const bf16x8*>(fb2 + j * 16 * BK);
#pragma unroll
            for (int i = 0; i < MI; ++i)
#pragma unroll
                for (int j = 0; j < NJ; ++j) {
                    acc[i][j] = __builtin_amdgcn_mfma_f32_16x16x32_bf16(
                        af[i], bf[j], acc[i][j], 0, 0, 0);
                    acc2[i][j] = __builtin_amdgcn_mfma_f32_16x16x32_bf16(
                        af[i], bg[j], acc2[i][j], 0, 0, 0);
                }
        } else {
#pragma unroll
            for (int i = 0; i < MI; ++i)
#pragma unroll
                for (int j = 0; j < NJ; ++j)
                    acc[i][j] = __builtin_amdgcn_mfma_f32_16x16x32_bf16(
                        af[i], bf[j], acc[i][j], 0, 0, 0);
        }
        __syncthreads();
    }

    // epilogue: C[row = wm+i*16+q*4+r][col = wn+j*16+r16]
    int mb = m0 + wm + q * 4;
    int nb = n0 + wn + r16;
    long bF = (long)b * Ff;
    float rs = 0.f, invtr = 0.f;
    if constexpr (MODE == 3) rs = 1.0f / sqrtf(scal[b]);
    if constexpr (MODE == 0 || MODE == 4 || MODE == 6) invtr = 1.0f / scal[b];
#pragma unroll
    for (int i = 0; i < MI; ++i) {
#pragma unroll
        for (int j = 0; j < NJ; ++j) {
#pragma unroll
            for (int r = 0; r < 4; ++r) {
                int m = mb + i * 16 + r;
                int n = nb + j * 16;
                long idx = (long)b * strideC + (long)m * ldc + n;
                float v = acc[i][j][r];
                if constexpr (MODE == 0) {
                    float bm_m = mbar[bF + m], bm_n = mbar[bF + n];
                    float mv_m = mv[bF + m], mv_n = mv[bF + n];
                    float corr = 2048.0f * (bm_m * mv_n + mv_m * bm_n - mv_m * mv_n);
                    float rc = aux32[(long)m * ldc + n];
                    float d = (m == n) ? 1e-5f : 0.0f;
                    float sig = 0.9f * rc + 0.1f * ((v - corr) * (1.0f / 2047.0f) + d);
                    out32[idx] = sig;
                    out16[idx] = f2bf(sig * invtr);
                } else if constexpr (MODE == 2) {
                    float pn = 1.5f * out32[idx] - 0.5f * v;
                    out32[idx] = pn;
                    out16[idx] = f2bf(pn);
                } else if constexpr (MODE == 3) {
                    out32[idx] = (v - vvec[bF + n]) * rs;
                } else if constexpr (MODE == 4) {
                    float p1 = ((m == n) ? 1.5f : 0.0f) - 0.5f * aux32[idx] * invtr;
                    float pn = 1.5f * p1 - 0.5f * v;
                    out32[idx] = pn;
                    out16[idx] = f2bf(pn);
                } else if constexpr (MODE == 6) {
                    float sn = aux32[idx] * invtr;
                    float dt = (m == n) ? 2.25f : 0.0f;
                    out16[idx]  = f2bf(dt - 1.5f * sn + 0.25f * v);
                    out16b[idx] = f2bf(1.5f * sn - 0.5f * v);
                } else if constexpr (MODE == 7) {
                    out16[idx] = f2bf(1.5f * aux32[idx] - 0.5f * v);
                } else if constexpr (MODE == 8) {
                    out16[idx]  = f2bf(v);
                    out16b[idx] = f2bf(acc2[i][j][r]);
                } else {
                    out32[idx] = v;
                }
            }
        }
    }
}

// ---------------------------------------------------------------------------
// K6: vvec[b][n] = sum_k mv[b][k] * P16[b][k][n]
__global__ __launch_bounds__(256) void mvecp(
    const float* __restrict__ mv, const unsigned short* __restrict__ P16,
    float* __restrict__ vvec) {
    int b = blockIdx.x;
    int n = blockIdx.y * 256 + threadIdx.x;
    const unsigned short* P = P16 + (long)b * Ff * Ff + n;
    const float* m = mv + (long)b * Ff;
    float a0 = 0.f, a1 = 0.f, a2 = 0.f, a3 = 0.f;
    for (int k = 0; k < Ff; k += 4) {
        a0 += m[k]     * bf2f(P[(long)k * Ff]);
        a1 += m[k + 1] * bf2f(P[(long)(k + 1) * Ff]);
        a2 += m[k + 2] * bf2f(P[(long)(k + 2) * Ff]);
        a3 += m[k + 3] * bf2f(P[(long)(k + 3) * Ff]);
    }
    vvec[(long)b * Ff + n] = (a0 + a1) + (a2 + a3);
}

// ---------------------------------------------------------------------------
extern "C" void kernel_launch(void* const* d_in, const int* in_sizes, int n_in,
                              void* d_out, int out_size, void* d_ws, size_t ws_size,
                              hipStream_t stream) {
    const float* x    = (const float*)d_in[0];
    const float* rm   = (const float*)d_in[1];
    const float* rcov = (const float*)d_in[2];
    float* out = (float*)d_out;

    char* ws = (char*)d_ws;
    unsigned short* x16   = (unsigned short*)(ws);                 // 64 MB
    unsigned short* xT16  = (unsigned short*)(ws + 67108864L);     // 64 MB
    float*          sig32 = (float*)(ws + 134217728L);             // 32 MB
    float*          P32   = (float*)(ws + 167772160L);             // 32 MB
    unsigned short* S16   = (unsigned short*)(ws + 201326592L);    // 16 MB
    unsigned short* P16   = (unsigned short*)(ws + 218103808L);    // 16 MB
    unsigned short* T16   = (unsigned short*)(ws + 234881024L);    // 16 MB
    unsigned short* U16   = (unsigned short*)(ws + 251658240L);    // 16 MB
    float*          msum_p= (float*)(ws + 268435456L);             // 2 MB
    float*          mbar  = (float*)(ws + 270532608L);             // 64 KB
    float*          mv    = (float*)(ws + 270598144L);             // 64 KB
    float*          vvec  = (float*)(ws + 270663680L);             // 64 KB
    float*          scal  = (float*)(ws + 270729216L);             // 128 B
    float*          msumsq_p = (float*)d_out;  // 2 MB scratch, overwritten by final

    const long sFF = (long)Ff * Ff;
    const long sSF = (long)Ss * Ff;

    cast_transpose<<<dim3(Ss / 64, Ff / 64, Bb), 256, 0, stream>>>(
        x, x16, xT16, msum_p, msumsq_p);
    meanred<<<Bb, 256, 0, stream>>>(msum_p, msumsq_p, rm, rcov, mbar, mv, scal);

    // sigma (fp32) + S16 = bf16(sigma/tr); 64x128 tiles -> 1024 blocks (4/CU)
    gemm_bt<0, 64, 128, 8, 4><<<1024, 256, 0, stream>>>(
        xT16, Ss, sSF, xT16, Ss, sSF, nullptr, Ss,
        rcov, sig32, S16, nullptr, mbar, mv, nullptr, scal, Ff, sFF);

    // G1: W = sn^2, fused T/U epilogue (T = P1^2, U = P1*sn)
    gemm_bt<6, 128, 64, 4, 8><<<1024, 256, 0, stream>>>(
        S16, Ff, sFF, S16, Ff, sFF, nullptr, Ff,
        sig32, nullptr, T16, U16, nullptr, nullptr, nullptr, scal, Ff, sFF);
    // G2: P2 = 1.5 P1 - 0.5 T*U   (P1 from sigma inline)
    gemm_bt<4, 128, 64, 4, 8><<<1024, 256, 0, stream>>>(
        T16, Ff, sFF, U16, Ff, sFF, nullptr, Ff,
        sig32, P32, P16, nullptr, nullptr, nullptr, nullptr, scal, Ff, sFF);

    // iter 3: fused dual {T=P^2, U=P*sn} then P3 = 1.5P - 0.5 T*U (keeps P32)
    gemm_bt<8, 128, 64, 4, 8><<<1024, 256, 0, stream>>>(
        P16, Ff, sFF, P16, Ff, sFF, S16, Ff,
        nullptr, nullptr, T16, U16, nullptr, nullptr, nullptr, nullptr, Ff, sFF);
    gemm_bt<2, 128, 64, 4, 8><<<1024, 256, 0, stream>>>(
        T16, Ff, sFF, U16, Ff, sFF, nullptr, Ff,
        nullptr, P32, P16, nullptr, nullptr, nullptr, nullptr, nullptr, Ff, sFF);
    // iter 4: fused dual, then P4 = 1.5P - 0.5 T*U, bf16 output only
    gemm_bt<8, 128, 64, 4, 8><<<1024, 256, 0, stream>>>(
        P16, Ff, sFF, P16, Ff, sFF, S16, Ff,
        nullptr, nullptr, T16, U16, nullptr, nullptr, nullptr, nullptr, Ff, sFF);
    gemm_bt<7, 128, 64, 4, 8><<<1024, 256, 0, stream>>>(
        T16, Ff, sFF, U16, Ff, sFF, nullptr, Ff,
        P32, nullptr, P16, nullptr, nullptr, nullptr, nullptr, nullptr, Ff, sFF);

    mvecp<<<dim3(Bb, 2), 256, 0, stream>>>(mv, P16, vvec);

    // out = (x@P4 - mv@P4) * tr^{-1/2}
    gemm_bt<3, 128, 128, 16, 4><<<2048, 256, 0, stream>>>(
        x16, Ff, sSF, P16, Ff, sFF, nullptr, Ff,
        nullptr, out, nullptr, nullptr, nullptr, nullptr, vvec, scal, Ff, sSF);
}

// Round 3
// 510.550 us; speedup vs baseline: 1.1462x; 1.0550x over previous
//
#include <hip/hip_runtime.h>

// ---------------------------------------------------------------------------
// Whitening2d: B=32, S=2048, F=512, fp32 in/out.
//   K1 (cast_colsum): streaming x -> x16 (bf16) + col sums/sumsq. No transpose.
//   K2 (meanred): mbar, mv, trace(sigma) -> scal[b]
//   gram_tn: sigma = 0.9 rcov + 0.1((x^T x - corr)/2047 + eps I), S16 = sigma/tr
//            TN-form from row-major x16 via ds_read_b64_tr_b16 fragments.
//            Triangle tiles (exact symmetry) + mirrored writes.
//   G1 (MODE 6, TRI): W = sn^2 -> T,U (exact symmetric, triangle+mirror)
//   G2 (MODE 4): P2 = 1.5 P1 - 0.5 T*U
//   iters 3,4: MODE 8 dual {T=P^2, U=P*sn}; MODE 2 / MODE 7 P-update
//   final (MODE 3): out = (x@P4 - mv@P4) * tr^{-1/2}
//   All GEMMs: 2-phase double-buffered global_load_lds staging (1 barrier/step).
// ---------------------------------------------------------------------------

#define Bb 32
#define Ss 2048
#define Ff 512

typedef __attribute__((ext_vector_type(8))) short bf16x8;
typedef __attribute__((ext_vector_type(4))) short bf16x4;
typedef __attribute__((ext_vector_type(8))) short short8;
typedef __attribute__((ext_vector_type(4))) float f32x4;

__device__ __forceinline__ unsigned short f2bf(float f) {
    unsigned int u = __float_as_uint(f);
    u += 0x7fffu + ((u >> 16) & 1u);   // RTNE
    return (unsigned short)(u >> 16);
}
__device__ __forceinline__ float bf2f(unsigned short u) {
    return __uint_as_float(((unsigned int)u) << 16);
}

__device__ __forceinline__ void gload_lds16(const void* g, void* l) {
    __builtin_amdgcn_global_load_lds(
        (const __attribute__((address_space(1))) void*)g,
        (__attribute__((address_space(3))) void*)l,
        16, 0, 0);
}

// ds_read_b64_tr_b16: per-lane gather of 4 bf16 at +0,+32,+64,+96 bytes.
// Two reads (offset 0 / 128B) give k = q*8+0..7 from [32s][16f] subtiles.
__device__ __forceinline__ bf16x8 tr_read(unsigned addr) {
    bf16x4 lo, hi;
    asm volatile("ds_read_b64_tr_b16 %0, %2\n\t"
                 "ds_read_b64_tr_b16 %1, %2 offset:128"
                 : "=&v"(lo), "=&v"(hi)
                 : "v"(addr));
    return __builtin_shufflevector(lo, hi, 0, 1, 2, 3, 4, 5, 6, 7);
}

// ---------------------------------------------------------------------------
// K1: pure streaming: x -> x16, col-sums + col-sumsq partials.
// grid (32 s-chunks, 32 b), block 256. Wave loads 2KB contiguous/instr.
// Cross-wave reduce via XOR-swizzled LDS (stores conflict-free, reads 2-way).
__global__ __launch_bounds__(256) void cast_colsum(
    const float* __restrict__ x, unsigned short* __restrict__ x16,
    float* __restrict__ msum_p, float* __restrict__ msumsq_p) {
    __shared__ float redm[4 * 512];
    __shared__ float redq[4 * 512];
    int b = blockIdx.y, sc = blockIdx.x;
    int t = threadIdx.x;
    int fi = t & 63, wr = t >> 6;
    long base = ((long)b * Ss + sc * 64 + wr) * Ff + fi * 8;
    const float* px = x + base;
    unsigned short* p16 = x16 + base;
    float sm[8] = {0.f, 0.f, 0.f, 0.f, 0.f, 0.f, 0.f, 0.f};
    float sq[8] = {0.f, 0.f, 0.f, 0.f, 0.f, 0.f, 0.f, 0.f};
#pragma unroll 4
    for (int i = 0; i < 16; ++i) {
        const float* p = px + (long)i * 4 * Ff;
        float4 v0 = *reinterpret_cast<const float4*>(p);
        float4 v1 = *reinterpret_cast<const float4*>(p + 4);
        short8 hv;
        hv[0] = (short)f2bf(v0.x); hv[1] = (short)f2bf(v0.y);
        hv[2] = (short)f2bf(v0.z); hv[3] = (short)f2bf(v0.w);
        hv[4] = (short)f2bf(v1.x); hv[5] = (short)f2bf(v1.y);
        hv[6] = (short)f2bf(v1.z); hv[7] = (short)f2bf(v1.w);
        *reinterpret_cast<short8*>(p16 + (long)i * 4 * Ff) = hv;
        sm[0] += v0.x; sq[0] += v0.x * v0.x;
        sm[1] += v0.y; sq[1] += v0.y * v0.y;
        sm[2] += v0.z; sq[2] += v0.z * v0.z;
        sm[3] += v0.w; sq[3] += v0.w * v0.w;
        sm[4] += v1.x; sq[4] += v1.x * v1.x;
        sm[5] += v1.y; sq[5] += v1.y * v1.y;
        sm[6] += v1.z; sq[6] += v1.z * v1.z;
        sm[7] += v1.w; sq[7] += v1.w * v1.w;
    }
    // element f = fi*8+e stored at [e*64 + (fi ^ (e<<3))]: stores conflict-free
#pragma unroll
    for (int e = 0; e < 8; ++e) {
        int idx = e * 64 + (fi ^ (e << 3));
        redm[wr * 512 + idx] = sm[e];
        redq[wr * 512 + idx] = sq[e];
    }
    __syncthreads();
#pragma unroll
    for (int h = 0; h < 2; ++h) {
        int f = t + h * 256;
        int e = f & 7, a = f >> 3;
        int idx = e * 64 + (a ^ (e << 3));
        float s = (redm[idx] + redm[512 + idx]) + (redm[1024 + idx] + redm[1536 + idx]);
        float qq = (redq[idx] + redq[512 + idx]) + (redq[1024 + idx] + redq[1536 + idx]);
        msum_p[((long)b * 32 + sc) * Ff + f] = s;
        msumsq_p[((long)b * 32 + sc) * Ff + f] = qq;
    }
}

// ---------------------------------------------------------------------------
// K2: reduce partials -> mbar, mv, trace(sigma) -> scal[b]
__global__ __launch_bounds__(256) void meanred(
    const float* __restrict__ msum_p, const float* __restrict__ msumsq_p,
    const float* __restrict__ rm, const float* __restrict__ rcov,
    float* __restrict__ mbar, float* __restrict__ mv,
    float* __restrict__ scal) {
    int b = blockIdx.x, t = threadIdx.x;
    float tp = 0.f;
#pragma unroll
    for (int h = 0; h < 2; ++h) {
        int f = t + h * 256;
        float s = 0.f, q = 0.f;
#pragma unroll 8
        for (int st = 0; st < 32; ++st) {
            s += msum_p[((long)b * 32 + st) * Ff + f];
            q += msumsq_p[((long)b * 32 + st) * Ff + f];
        }
        float mb_ = s * (1.0f / 2048.0f);
        float mvv = 0.9f * rm[f] + 0.1f * mb_;
        mbar[b * Ff + f] = mb_;
        mv[b * Ff + f] = mvv;
        float corr = 2048.0f * (2.0f * mb_ * mvv - mvv * mvv);
        float rc = rcov[(long)f * Ff + f];
        tp += 0.9f * rc + 0.1f * ((q - corr) * (1.0f / 2047.0f) + 1e-5f);
    }
    __shared__ float red[4];
#pragma unroll
    for (int off = 32; off; off >>= 1) tp += __shfl_down(tp, off, 64);
    if ((t & 63) == 0) red[t >> 6] = tp;
    __syncthreads();
    if (t == 0) scal[b] = (red[0] + red[1]) + (red[2] + red[3]);
}

// ---------------------------------------------------------------------------
// Sigma: TN Gram from row-major x16. 64x128 tiles, triangle (20/32) + mirror.
// LDS per buffer: A 4 chunks + B 8 chunks of [32 s][16 f] ushorts (12KB); dbuf.
__global__ __launch_bounds__(256, 2) void gram_tn(
    const unsigned short* __restrict__ x16,
    const float* __restrict__ rcov,
    const float* __restrict__ mbar, const float* __restrict__ mv,
    const float* __restrict__ scal,
    float* __restrict__ sig32, unsigned short* __restrict__ S16) {
    constexpr int SZ = 6144;               // ushorts per buffer
    __shared__ unsigned short sAll[2 * SZ];
    int lin = blockIdx.x;
    int g = lin >> 3;
    int b = (lin & 7) * 4 + g / 20;
    int kt = g % 20;
    int mi, nj;
    if      (kt < 4)  { mi = 0; nj = kt; }
    else if (kt < 8)  { mi = 1; nj = kt - 4; }
    else if (kt < 11) { mi = 2; nj = kt - 7; }
    else if (kt < 14) { mi = 3; nj = kt - 10; }
    else if (kt < 16) { mi = 4; nj = kt - 12; }
    else if (kt < 18) { mi = 5; nj = kt - 14; }
    else if (kt < 19) { mi = 6; nj = 3; }
    else              { mi = 7; nj = 3; }
    int m0 = mi * 64, n0 = nj * 128;

    int t = threadIdx.x;
    int w = t >> 6, l = t & 63;
    int wm = (w >> 1) * 32, wn = (w & 1) * 64;
    int q = l >> 4, r16 = l & 15;

    const unsigned short* gx = x16 + (long)b * Ss * Ff;
    int s_ld = (t >> 1) & 31;
    int aoff = m0 + (t >> 6) * 16 + (t & 1) * 8;
    int boff = n0 + (t >> 6) * 16 + (t & 1) * 8;
    const unsigned short* srow = gx + (long)s_ld * Ff;

    f32x4 acc[2][4] = {};
    unsigned aB = (unsigned)(unsigned long long)
        &sAll[((w >> 1) * 2) * 512 + q * 128 + r16];
    unsigned bB = (unsigned)(unsigned long long)
        &sAll[2048 + ((w & 1) * 4) * 512 + q * 128 + r16];

    // prologue: stage buf0
    {
        unsigned short* d0 = &sAll[t * 8];
        gload_lds16(srow + aoff, d0);
        gload_lds16(srow + boff, d0 + 2048);
        gload_lds16(srow + boff + 64, d0 + 4096);
    }
    __syncthreads();

    int cur = 0;
    for (int k0 = 0; k0 < Ss; k0 += 32) {
        if (k0 + 32 < Ss) {
            const unsigned short* sr = srow + (long)(k0 + 32) * Ff;
            unsigned short* dd = &sAll[(cur ^ 1) * SZ + t * 8];
            gload_lds16(sr + aoff, dd);
            gload_lds16(sr + boff, dd + 2048);
            gload_lds16(sr + boff + 64, dd + 4096);
        }
        unsigned ab = aB + (unsigned)(cur * (SZ * 2));
        unsigned bb = bB + (unsigned)(cur * (SZ * 2));
        bf16x8 a0 = tr_read(ab);
        bf16x8 a1 = tr_read(ab + 1024);
        bf16x8 b0 = tr_read(bb);
        bf16x8 b1 = tr_read(bb + 1024);
        bf16x8 b2 = tr_read(bb + 2048);
        bf16x8 b3 = tr_read(bb + 3072);
        asm volatile("s_waitcnt lgkmcnt(0)" ::: "memory");
        __builtin_amdgcn_sched_barrier(0);
        acc[0][0] = __builtin_amdgcn_mfma_f32_16x16x32_bf16(a0, b0, acc[0][0], 0, 0, 0);
        acc[0][1] = __builtin_amdgcn_mfma_f32_16x16x32_bf16(a0, b1, acc[0][1], 0, 0, 0);
        acc[0][2] = __builtin_amdgcn_mfma_f32_16x16x32_bf16(a0, b2, acc[0][2], 0, 0, 0);
        acc[0][3] = __builtin_amdgcn_mfma_f32_16x16x32_bf16(a0, b3, acc[0][3], 0, 0, 0);
        acc[1][0] = __builtin_amdgcn_mfma_f32_16x16x32_bf16(a1, b0, acc[1][0], 0, 0, 0);
        acc[1][1] = __builtin_amdgcn_mfma_f32_16x16x32_bf16(a1, b1, acc[1][1], 0, 0, 0);
        acc[1][2] = __builtin_amdgcn_mfma_f32_16x16x32_bf16(a1, b2, acc[1][2], 0, 0, 0);
        acc[1][3] = __builtin_amdgcn_mfma_f32_16x16x32_bf16(a1, b3, acc[1][3], 0, 0, 0);
        __syncthreads();
        cur ^= 1;
    }

    // epilogue: sigma + S16, primary scalar + mirrored vector writes
    int mb = m0 + wm + q * 4;
    int nb = n0 + wn + r16;
    long bF = (long)b * Ff;
    long bS = (long)b * Ff * Ff;
    float invtr = 1.0f / scal[b];
#pragma unroll
    for (int i = 0; i < 2; ++i) {
#pragma unroll
        for (int j = 0; j < 4; ++j) {
            int n = nb + j * 16;
            float bm_n = mbar[bF + n], mv_n = mv[bF + n];
            float s4[4];
            unsigned short h4[4];
#pragma unroll
            for (int r = 0; r < 4; ++r) {
                int m = mb + i * 16 + r;
                float bm_m = mbar[bF + m], mv_m = mv[bF + m];
                float corr = 2048.0f * (bm_m * mv_n + mv_m * bm_n - mv_m * mv_n);
                float rc = rcov[(long)m * Ff + n];
                float d = (m == n) ? 1e-5f : 0.0f;
                float sig = 0.9f * rc + 0.1f * ((acc[i][j][r] - corr) * (1.0f / 2047.0f) + d);
                long idx = bS + (long)m * Ff + n;
                sig32[idx] = sig;
                unsigned short hh = f2bf(sig * invtr);
                S16[idx] = hh;
                s4[r] = sig; h4[r] = hh;
            }
            long midx = bS + (long)n * Ff + (mb + i * 16);
            *reinterpret_cast<float4*>(&sig32[midx]) =
                make_float4(s4[0], s4[1], s4[2], s4[3]);
            ushort4 hm; hm.x = h4[0]; hm.y = h4[1]; hm.z = h4[2]; hm.w = h4[3];
            *reinterpret_cast<ushort4*>(&S16[midx]) = hm;
        }
    }
}

// ---------------------------------------------------------------------------
// K3: BT-form GEMM, 2-phase double-buffered staging.
// MODE 2: P' = 1.5*out32 - 0.5C -> out32 (rw), out16
// MODE 3: out = (C - vvec[n]) * rsqrt(tr) -> out32
// MODE 4: p1 = 1.5I - 0.5*aux32/tr; P'=1.5p1-0.5C -> out32, out16
// MODE 6: sn=aux32/tr; T=2.25I-1.5sn+0.25C, U=1.5sn-0.5C (TRI: +mirrors)
// MODE 7: P' = 1.5*aux32 - 0.5C -> out16 only
// MODE 8: fused dual: out16 = bf16(A*Bt^T), out16b = bf16(A*B2^T)
#define BK 32

template <int MODE, int BM, int BN, int MT, int NT, bool TRI>
__global__ __launch_bounds__(256, (MODE == 8 ? 3 : (BM * BN <= 8192 ? 4 : 3)))
void gemm_bt(
    const unsigned short* __restrict__ A, int lda, long strideA,
    const unsigned short* __restrict__ Bt, int ldb, long strideB,
    const unsigned short* __restrict__ B2, int K,
    const float* __restrict__ aux32,
    float* __restrict__ out32,
    unsigned short* __restrict__ out16,
    unsigned short* __restrict__ out16b,
    const float* __restrict__ vvec,
    float* __restrict__ scal,
    int ldc, long strideC) {
    constexpr bool FUSE = (MODE == 8);
    constexpr int AR = BM / 64, BR = BN / 64;
    constexpr int WM = BM / 2, WN = BN / 2;
    constexpr int MI = WM / 16, NJ = WN / 16;
    constexpr int ATOT = BM * BK, BTOT = BN * BK;
    constexpr int SZ = ATOT + BTOT + (FUSE ? BTOT : 0);
    __shared__ unsigned short sAll[2 * SZ];

    int lin = blockIdx.x;
    int b, m0, n0;
    if constexpr (TRI) {
        static_assert(BM == 128 && BN == 64, "TRI table assumes 128x64");
        int g = lin >> 3;
        b = (lin & 7) * 4 + g / 20;
        int kt = g % 20;
        int mi, nj;
        if      (kt < 8)  { mi = 0; nj = kt; }
        else if (kt < 14) { mi = 1; nj = kt - 6; }
        else if (kt < 18) { mi = 2; nj = kt - 10; }
        else              { mi = 3; nj = kt - 12; }
        m0 = mi * BM; n0 = nj * BN;
    } else {
        constexpr int NTILES = MT * NT;
        constexpr int TB = (NTILES == 16) ? 4 : ((NTILES == 32) ? 5 : 6);
        b = (lin & 7) * 4 + (lin >> (3 + TB));
        int tile = (lin >> 3) & (NTILES - 1);
        m0 = (tile & (MT - 1)) * BM;
        n0 = (tile / MT) * BN;
    }

    int t = threadIdx.x;
    int w = t >> 6, l = t & 63;
    int wm = (w >> 1) * WM, wn = (w & 1) * WN;

    const unsigned short* gA = A + (long)b * strideA;
    const unsigned short* gB = Bt + (long)b * strideB;

    int srow = t >> 2, sk = (t & 3) * 8;
    const unsigned short* pa[AR];
    const unsigned short* pb[BR];
    const unsigned short* pb2[FUSE ? BR : 1];
#pragma unroll
    for (int r = 0; r < AR; ++r) pa[r] = gA + (long)(m0 + r * 64 + srow) * lda + sk;
#pragma unroll
    for (int r = 0; r < BR; ++r) pb[r] = gB + (long)(n0 + r * 64 + srow) * ldb + sk;
    if constexpr (FUSE) {
        const unsigned short* g2 = B2 + (long)b * strideB;
#pragma unroll
        for (int r = 0; r < BR; ++r)
            pb2[r] = g2 + (long)(n0 + r * 64 + srow) * ldb + sk;
    }

    int q = l >> 4, r16 = l & 15;
    int faOff = (wm + r16) * BK + q * 8;
    int fbOff = ATOT + (wn + r16) * BK + q * 8;
    int fb2Off = ATOT + BTOT + (wn + r16) * BK + q * 8;

    f32x4 acc[MI][NJ] = {};
    f32x4 acc2[FUSE ? MI : 1][FUSE ? NJ : 1] = {};

    auto stage = [&](int buf) {
        unsigned short* dA = &sAll[buf * SZ + t * 8];
#pragma unroll
        for (int r = 0; r < AR; ++r) { gload_lds16(pa[r], dA + r * 2048); pa[r] += BK; }
        unsigned short* dB = &sAll[buf * SZ + ATOT + t * 8];
#pragma unroll
        for (int r = 0; r < BR; ++r) { gload_lds16(pb[r], dB + r * 2048); pb[r] += BK; }
        if constexpr (FUSE) {
            unsigned short* dB2 = &sAll[buf * SZ + ATOT + BTOT + t * 8];
#pragma unroll
            for (int r = 0; r < BR; ++r) { gload_lds16(pb2[r], dB2 + r * 2048); pb2[r] += BK; }
        }
    };

    stage(0);
    __syncthreads();
    int cur = 0;
    for (int k0 = 0; k0 < K; k0 += BK) {
        if (k0 + BK < K) stage(cur ^ 1);
        const unsigned short* bufc = &sAll[cur * SZ];
        bf16x8 af[MI], bfr[NJ];
#pragma unroll
        for (int i = 0; i < MI; ++i)
            af[i] = *reinterpret_cast<const bf16x8*>(bufc + faOff + i * 16 * BK);
#pragma unroll
        for (int j = 0; j < NJ; ++j)
            bfr[j] = *reinterpret_cast<const bf16x8*>(bufc + fbOff + j * 16 * BK);
        if constexpr (FUSE) {
            bf16x8 bg[NJ];
#pragma unroll
            for (int j = 0; j < NJ; ++j)
                bg[j] = *reinterpret_cast<const bf16x8*>(bufc + fb2Off + j * 16 * BK);
#pragma unroll
            for (int i = 0; i < MI; ++i)
#pragma unroll
                for (int j = 0; j < NJ; ++j) {
                    acc[i][j] = __builtin_amdgcn_mfma_f32_16x16x32_bf16(
                        af[i], bfr[j], acc[i][j], 0, 0, 0);
                    acc2[i][j] = __builtin_amdgcn_mfma_f32_16x16x32_bf16(
                        af[i], bg[j], acc2[i][j], 0, 0, 0);
                }
        } else {
#pragma unroll
            for (int i = 0; i < MI; ++i)
#pragma unroll
                for (int j = 0; j < NJ; ++j)
                    acc[i][j] = __builtin_amdgcn_mfma_f32_16x16x32_bf16(
                        af[i], bfr[j], acc[i][j], 0, 0, 0);
        }
        __syncthreads();
        cur ^= 1;
    }

    // epilogue: C[row = wm+i*16+q*4+r][col = wn+j*16+r16]
    int mb = m0 + wm + q * 4;
    int nb = n0 + wn + r16;
    long bF = (long)b * Ff;
    float rs = 0.f, invtr = 0.f;
    if constexpr (MODE == 3) rs = 1.0f / sqrtf(scal[b]);
    if constexpr (MODE == 4 || MODE == 6) invtr = 1.0f / scal[b];
#pragma unroll
    for (int i = 0; i < MI; ++i) {
#pragma unroll
        for (int j = 0; j < NJ; ++j) {
            int n = nb + j * 16;
            if constexpr (MODE == 6) {
                unsigned short tq[4], uq[4];
#pragma unroll
                for (int r = 0; r < 4; ++r) {
                    int m = mb + i * 16 + r;
                    long idx = (long)b * strideC + (long)m * ldc + n;
                    float v = acc[i][j][r];
                    float sn = aux32[idx] * invtr;
                    float dt = (m == n) ? 2.25f : 0.0f;
                    tq[r] = f2bf(dt - 1.5f * sn + 0.25f * v);
                    uq[r] = f2bf(1.5f * sn - 0.5f * v);
                    out16[idx] = tq[r];
                    out16b[idx] = uq[r];
                }
                if constexpr (TRI) {
                    long midx = (long)b * strideC + (long)n * ldc + (mb + i * 16);
                    ushort4 mt; mt.x = tq[0]; mt.y = tq[1]; mt.z = tq[2]; mt.w = tq[3];
                    ushort4 mu; mu.x = uq[0]; mu.y = uq[1]; mu.z = uq[2]; mu.w = uq[3];
                    *reinterpret_cast<ushort4*>(&out16[midx]) = mt;
                    *reinterpret_cast<ushort4*>(&out16b[midx]) = mu;
                }
            } else {
#pragma unroll
                for (int r = 0; r < 4; ++r) {
                    int m = mb + i * 16 + r;
                    long idx = (long)b * strideC + (long)m * ldc + n;
                    float v = acc[i][j][r];
                    if constexpr (MODE == 2) {
                        float pn = 1.5f * out32[idx] - 0.5f * v;
                        out32[idx] = pn;
                        out16[idx] = f2bf(pn);
                    } else if constexpr (MODE == 3) {
                        out32[idx] = (v - vvec[bF + n]) * rs;
                    } else if constexpr (MODE == 4) {
                        float p1 = ((m == n) ? 1.5f : 0.0f) - 0.5f * aux32[idx] * invtr;
                        float pn = 1.5f * p1 - 0.5f * v;
                        out32[idx] = pn;
                        out16[idx] = f2bf(pn);
                    } else if constexpr (MODE == 7) {
                        out16[idx] = f2bf(1.5f * aux32[idx] - 0.5f * v);
                    } else if constexpr (MODE == 8) {
                        out16[idx] = f2bf(v);
                        out16b[idx] = f2bf(acc2[i][j][r]);
                    } else {
                        out32[idx] = v;
                    }
                }
            }
        }
    }
}

// ---------------------------------------------------------------------------
// K6: vvec[b][n] = sum_k mv[b][k] * P16[b][k][n]
__global__ __launch_bounds__(256) void mvecp(
    const float* __restrict__ mv, const unsigned short* __restrict__ P16,
    float* __restrict__ vvec) {
    int b = blockIdx.x;
    int n = blockIdx.y * 256 + threadIdx.x;
    const unsigned short* P = P16 + (long)b * Ff * Ff + n;
    const float* m = mv + (long)b * Ff;
    float a0 = 0.f, a1 = 0.f, a2 = 0.f, a3 = 0.f;
    for (int k = 0; k < Ff; k += 4) {
        a0 += m[k]     * bf2f(P[(long)k * Ff]);
        a1 += m[k + 1] * bf2f(P[(long)(k + 1) * Ff]);
        a2 += m[k + 2] * bf2f(P[(long)(k + 2) * Ff]);
        a3 += m[k + 3] * bf2f(P[(long)(k + 3) * Ff]);
    }
    vvec[(long)b * Ff + n] = (a0 + a1) + (a2 + a3);
}

// ---------------------------------------------------------------------------
extern "C" void kernel_launch(void* const* d_in, const int* in_sizes, int n_in,
                              void* d_out, int out_size, void* d_ws, size_t ws_size,
                              hipStream_t stream) {
    const float* x    = (const float*)d_in[0];
    const float* rm   = (const float*)d_in[1];
    const float* rcov = (const float*)d_in[2];
    float* out = (float*)d_out;

    char* ws = (char*)d_ws;
    unsigned short* x16   = (unsigned short*)(ws);                 // 64 MB
    // 64 MB at +67108864 free (was xT16)
    float*          sig32 = (float*)(ws + 134217728L);             // 32 MB
    float*          P32   = (float*)(ws + 167772160L);             // 32 MB
    unsigned short* S16   = (unsigned short*)(ws + 201326592L);    // 16 MB
    unsigned short* P16   = (unsigned short*)(ws + 218103808L);    // 16 MB
    unsigned short* T16   = (unsigned short*)(ws + 234881024L);    // 16 MB
    unsigned short* U16   = (unsigned short*)(ws + 251658240L);    // 16 MB
    float*          msum_p= (float*)(ws + 268435456L);             // 2 MB
    float*          mbar  = (float*)(ws + 270532608L);             // 64 KB
    float*          mv    = (float*)(ws + 270598144L);             // 64 KB
    float*          vvec  = (float*)(ws + 270663680L);             // 64 KB
    float*          scal  = (float*)(ws + 270729216L);             // 128 B
    float*          msumsq_p = (float*)d_out;  // 2 MB scratch, overwritten by final

    const long sFF = (long)Ff * Ff;
    const long sSF = (long)Ss * Ff;

    cast_colsum<<<dim3(32, Bb), 256, 0, stream>>>(x, x16, msum_p, msumsq_p);
    meanred<<<Bb, 256, 0, stream>>>(msum_p, msumsq_p, rm, rcov, mbar, mv, scal);

    // sigma + S16, TN-form from x16, triangle + mirror
    gram_tn<<<640, 256, 0, stream>>>(x16, rcov, mbar, mv, scal, sig32, S16);

    // G1: W = sn^2 -> T,U (triangle + mirror, exact)
    gemm_bt<6, 128, 64, 4, 8, true><<<640, 256, 0, stream>>>(
        S16, Ff, sFF, S16, Ff, sFF, nullptr, Ff,
        sig32, nullptr, T16, U16, nullptr, scal, Ff, sFF);
    // G2: P2 = 1.5 P1 - 0.5 T*U
    gemm_bt<4, 128, 64, 4, 8, false><<<1024, 256, 0, stream>>>(
        T16, Ff, sFF, U16, Ff, sFF, nullptr, Ff,
        sig32, P32, P16, nullptr, nullptr, scal, Ff, sFF);

    // iter 3: fused dual {T=P^2, U=P*sn}; P3 = 1.5P - 0.5 T*U (keeps P32)
    gemm_bt<8, 128, 64, 4, 8, false><<<1024, 256, 0, stream>>>(
        P16, Ff, sFF, P16, Ff, sFF, S16, Ff,
        nullptr, nullptr, T16, U16, nullptr, nullptr, Ff, sFF);
    gemm_bt<2, 128, 64, 4, 8, false><<<1024, 256, 0, stream>>>(
        T16, Ff, sFF, U16, Ff, sFF, nullptr, Ff,
        nullptr, P32, P16, nullptr, nullptr, nullptr, Ff, sFF);
    // iter 4: fused dual; P4 = 1.5P - 0.5 T*U, bf16 only
    gemm_bt<8, 128, 64, 4, 8, false><<<1024, 256, 0, stream>>>(
        P16, Ff, sFF, P16, Ff, sFF, S16, Ff,
        nullptr, nullptr, T16, U16, nullptr, nullptr, Ff, sFF);
    gemm_bt<7, 128, 64, 4, 8, false><<<1024, 256, 0, stream>>>(
        T16, Ff, sFF, U16, Ff, sFF, nullptr, Ff,
        P32, nullptr, P16, nullptr, nullptr, nullptr, Ff, sFF);

    mvecp<<<dim3(Bb, 2), 256, 0, stream>>>(mv, P16, vvec);

    // out = (x@P4 - mv@P4) * tr^{-1/2}
    gemm_bt<3, 128, 128, 16, 4, false><<<2048, 256, 0, stream>>>(
        x16, Ff, sSF, P16, Ff, sFF, nullptr, Ff,
        nullptr, out, nullptr, nullptr, vvec, scal, Ff, sSF);
}

// Round 4
// 502.212 us; speedup vs baseline: 1.1652x; 1.0166x over previous
//
#include <hip/hip_runtime.h>

// ---------------------------------------------------------------------------
// Whitening2d: B=32, S=2048, F=512, fp32 in/out.
//   K1 (cast_colsum): streaming x -> x16 (bf16) + col sums/sumsq. No transpose.
//   K2 (meanred): mbar, mv, trace(sigma) -> scal[b]
//   gram_tn: sigma = 0.9 rcov + 0.1((x^T x - corr)/2047 + eps I), S16 = sigma/tr
//            TN-form from row-major x16 via ds_read_b64_tr_b16 fragments.
//            Triangle tiles (exact symmetry) + mirrored writes.
//   ALL NS-chain products are symmetric (polynomials in sn) -> every F x F GEMM
//   runs on 20/32 triangle tiles with mirrored epilogue writes; mirrors are
//   skipped on diagonal 128-blocks (their transposes are primaries), keeping
//   each output location single-writer (deterministic).
//   G1 (MODE 6, TRI): W = sn^2 -> T,U
//   G2 (MODE 4, TRI): P2 = 1.5 P1 - 0.5 T*U -> P32a, P16
//   iter 3: MODE 8 TRI dual {T=P^2, U=P*sn}; MODE 2 TRI: P3 = 1.5*P32a - 0.5 T*U
//           -> P32b, P16  (ping-pong: aux read, pure writes, no RMW race)
//   iter 4: MODE 8 TRI dual; MODE 7 TRI: P4 = 1.5*P32b - 0.5 T*U -> P16 only
//   final (MODE 3): out = (x@P4 - mv@P4) * tr^{-1/2}
//   All GEMMs: 2-phase double-buffered global_load_lds staging (1 barrier/step).
// ---------------------------------------------------------------------------

#define Bb 32
#define Ss 2048
#define Ff 512

typedef __attribute__((ext_vector_type(8))) short bf16x8;
typedef __attribute__((ext_vector_type(4))) short bf16x4;
typedef __attribute__((ext_vector_type(8))) short short8;
typedef __attribute__((ext_vector_type(4))) float f32x4;

__device__ __forceinline__ unsigned short f2bf(float f) {
    unsigned int u = __float_as_uint(f);
    u += 0x7fffu + ((u >> 16) & 1u);   // RTNE
    return (unsigned short)(u >> 16);
}
__device__ __forceinline__ float bf2f(unsigned short u) {
    return __uint_as_float(((unsigned int)u) << 16);
}

__device__ __forceinline__ void gload_lds16(const void* g, void* l) {
    __builtin_amdgcn_global_load_lds(
        (const __attribute__((address_space(1))) void*)g,
        (__attribute__((address_space(3))) void*)l,
        16, 0, 0);
}

// ds_read_b64_tr_b16: per-lane gather of 4 bf16 at +0,+32,+64,+96 bytes.
// Two reads (offset 0 / 128B) give k = q*8+0..7 from [32s][16f] subtiles.
__device__ __forceinline__ bf16x8 tr_read(unsigned addr) {
    bf16x4 lo, hi;
    asm volatile("ds_read_b64_tr_b16 %0, %2\n\t"
                 "ds_read_b64_tr_b16 %1, %2 offset:128"
                 : "=&v"(lo), "=&v"(hi)
                 : "v"(addr));
    return __builtin_shufflevector(lo, hi, 0, 1, 2, 3, 4, 5, 6, 7);
}

// ---------------------------------------------------------------------------
// K1: pure streaming: x -> x16, col-sums + col-sumsq partials.
__global__ __launch_bounds__(256) void cast_colsum(
    const float* __restrict__ x, unsigned short* __restrict__ x16,
    float* __restrict__ msum_p, float* __restrict__ msumsq_p) {
    __shared__ float redm[4 * 512];
    __shared__ float redq[4 * 512];
    int b = blockIdx.y, sc = blockIdx.x;
    int t = threadIdx.x;
    int fi = t & 63, wr = t >> 6;
    long base = ((long)b * Ss + sc * 64 + wr) * Ff + fi * 8;
    const float* px = x + base;
    unsigned short* p16 = x16 + base;
    float sm[8] = {0.f, 0.f, 0.f, 0.f, 0.f, 0.f, 0.f, 0.f};
    float sq[8] = {0.f, 0.f, 0.f, 0.f, 0.f, 0.f, 0.f, 0.f};
#pragma unroll 4
    for (int i = 0; i < 16; ++i) {
        const float* p = px + (long)i * 4 * Ff;
        float4 v0 = *reinterpret_cast<const float4*>(p);
        float4 v1 = *reinterpret_cast<const float4*>(p + 4);
        short8 hv;
        hv[0] = (short)f2bf(v0.x); hv[1] = (short)f2bf(v0.y);
        hv[2] = (short)f2bf(v0.z); hv[3] = (short)f2bf(v0.w);
        hv[4] = (short)f2bf(v1.x); hv[5] = (short)f2bf(v1.y);
        hv[6] = (short)f2bf(v1.z); hv[7] = (short)f2bf(v1.w);
        *reinterpret_cast<short8*>(p16 + (long)i * 4 * Ff) = hv;
        sm[0] += v0.x; sq[0] += v0.x * v0.x;
        sm[1] += v0.y; sq[1] += v0.y * v0.y;
        sm[2] += v0.z; sq[2] += v0.z * v0.z;
        sm[3] += v0.w; sq[3] += v0.w * v0.w;
        sm[4] += v1.x; sq[4] += v1.x * v1.x;
        sm[5] += v1.y; sq[5] += v1.y * v1.y;
        sm[6] += v1.z; sq[6] += v1.z * v1.z;
        sm[7] += v1.w; sq[7] += v1.w * v1.w;
    }
#pragma unroll
    for (int e = 0; e < 8; ++e) {
        int idx = e * 64 + (fi ^ (e << 3));
        redm[wr * 512 + idx] = sm[e];
        redq[wr * 512 + idx] = sq[e];
    }
    __syncthreads();
#pragma unroll
    for (int h = 0; h < 2; ++h) {
        int f = t + h * 256;
        int e = f & 7, a = f >> 3;
        int idx = e * 64 + (a ^ (e << 3));
        float s = (redm[idx] + redm[512 + idx]) + (redm[1024 + idx] + redm[1536 + idx]);
        float qq = (redq[idx] + redq[512 + idx]) + (redq[1024 + idx] + redq[1536 + idx]);
        msum_p[((long)b * 32 + sc) * Ff + f] = s;
        msumsq_p[((long)b * 32 + sc) * Ff + f] = qq;
    }
}

// ---------------------------------------------------------------------------
// K2: reduce partials -> mbar, mv, trace(sigma) -> scal[b]
__global__ __launch_bounds__(256) void meanred(
    const float* __restrict__ msum_p, const float* __restrict__ msumsq_p,
    const float* __restrict__ rm, const float* __restrict__ rcov,
    float* __restrict__ mbar, float* __restrict__ mv,
    float* __restrict__ scal) {
    int b = blockIdx.x, t = threadIdx.x;
    float tp = 0.f;
#pragma unroll
    for (int h = 0; h < 2; ++h) {
        int f = t + h * 256;
        float s = 0.f, q = 0.f;
#pragma unroll 8
        for (int st = 0; st < 32; ++st) {
            s += msum_p[((long)b * 32 + st) * Ff + f];
            q += msumsq_p[((long)b * 32 + st) * Ff + f];
        }
        float mb_ = s * (1.0f / 2048.0f);
        float mvv = 0.9f * rm[f] + 0.1f * mb_;
        mbar[b * Ff + f] = mb_;
        mv[b * Ff + f] = mvv;
        float corr = 2048.0f * (2.0f * mb_ * mvv - mvv * mvv);
        float rc = rcov[(long)f * Ff + f];
        tp += 0.9f * rc + 0.1f * ((q - corr) * (1.0f / 2047.0f) + 1e-5f);
    }
    __shared__ float red[4];
#pragma unroll
    for (int off = 32; off; off >>= 1) tp += __shfl_down(tp, off, 64);
    if ((t & 63) == 0) red[t >> 6] = tp;
    __syncthreads();
    if (t == 0) scal[b] = (red[0] + red[1]) + (red[2] + red[3]);
}

// ---------------------------------------------------------------------------
// Sigma: TN Gram from row-major x16. 64x128 tiles, triangle (20/32) + mirror.
__global__ __launch_bounds__(256, 2) void gram_tn(
    const unsigned short* __restrict__ x16,
    const float* __restrict__ rcov,
    const float* __restrict__ mbar, const float* __restrict__ mv,
    const float* __restrict__ scal,
    float* __restrict__ sig32, unsigned short* __restrict__ S16) {
    constexpr int SZ = 6144;               // ushorts per buffer
    __shared__ unsigned short sAll[2 * SZ];
    int lin = blockIdx.x;
    int g = lin >> 3;
    int b = (lin & 7) * 4 + g / 20;
    int kt = g % 20;
    int mi, nj;
    if      (kt < 4)  { mi = 0; nj = kt; }
    else if (kt < 8)  { mi = 1; nj = kt - 4; }
    else if (kt < 11) { mi = 2; nj = kt - 7; }
    else if (kt < 14) { mi = 3; nj = kt - 10; }
    else if (kt < 16) { mi = 4; nj = kt - 12; }
    else if (kt < 18) { mi = 5; nj = kt - 14; }
    else if (kt < 19) { mi = 6; nj = 3; }
    else              { mi = 7; nj = 3; }
    int m0 = mi * 64, n0 = nj * 128;

    int t = threadIdx.x;
    int w = t >> 6, l = t & 63;
    int wm = (w >> 1) * 32, wn = (w & 1) * 64;
    int q = l >> 4, r16 = l & 15;

    const unsigned short* gx = x16 + (long)b * Ss * Ff;
    int s_ld = (t >> 1) & 31;
    int aoff = m0 + (t >> 6) * 16 + (t & 1) * 8;
    int boff = n0 + (t >> 6) * 16 + (t & 1) * 8;
    const unsigned short* srow = gx + (long)s_ld * Ff;

    f32x4 acc[2][4] = {};
    unsigned aB = (unsigned)(unsigned long long)
        &sAll[((w >> 1) * 2) * 512 + q * 128 + r16];
    unsigned bB = (unsigned)(unsigned long long)
        &sAll[2048 + ((w & 1) * 4) * 512 + q * 128 + r16];

    {
        unsigned short* d0 = &sAll[t * 8];
        gload_lds16(srow + aoff, d0);
        gload_lds16(srow + boff, d0 + 2048);
        gload_lds16(srow + boff + 64, d0 + 4096);
    }
    __syncthreads();

    int cur = 0;
    for (int k0 = 0; k0 < Ss; k0 += 32) {
        if (k0 + 32 < Ss) {
            const unsigned short* sr = srow + (long)(k0 + 32) * Ff;
            unsigned short* dd = &sAll[(cur ^ 1) * SZ + t * 8];
            gload_lds16(sr + aoff, dd);
            gload_lds16(sr + boff, dd + 2048);
            gload_lds16(sr + boff + 64, dd + 4096);
        }
        unsigned ab = aB + (unsigned)(cur * (SZ * 2));
        unsigned bb = bB + (unsigned)(cur * (SZ * 2));
        bf16x8 a0 = tr_read(ab);
        bf16x8 a1 = tr_read(ab + 1024);
        bf16x8 b0 = tr_read(bb);
        bf16x8 b1 = tr_read(bb + 1024);
        bf16x8 b2 = tr_read(bb + 2048);
        bf16x8 b3 = tr_read(bb + 3072);
        asm volatile("s_waitcnt lgkmcnt(0)" ::: "memory");
        __builtin_amdgcn_sched_barrier(0);
        acc[0][0] = __builtin_amdgcn_mfma_f32_16x16x32_bf16(a0, b0, acc[0][0], 0, 0, 0);
        acc[0][1] = __builtin_amdgcn_mfma_f32_16x16x32_bf16(a0, b1, acc[0][1], 0, 0, 0);
        acc[0][2] = __builtin_amdgcn_mfma_f32_16x16x32_bf16(a0, b2, acc[0][2], 0, 0, 0);
        acc[0][3] = __builtin_amdgcn_mfma_f32_16x16x32_bf16(a0, b3, acc[0][3], 0, 0, 0);
        acc[1][0] = __builtin_amdgcn_mfma_f32_16x16x32_bf16(a1, b0, acc[1][0], 0, 0, 0);
        acc[1][1] = __builtin_amdgcn_mfma_f32_16x16x32_bf16(a1, b1, acc[1][1], 0, 0, 0);
        acc[1][2] = __builtin_amdgcn_mfma_f32_16x16x32_bf16(a1, b2, acc[1][2], 0, 0, 0);
        acc[1][3] = __builtin_amdgcn_mfma_f32_16x16x32_bf16(a1, b3, acc[1][3], 0, 0, 0);
        __syncthreads();
        cur ^= 1;
    }

    int mb = m0 + wm + q * 4;
    int nb = n0 + wn + r16;
    long bF = (long)b * Ff;
    long bS = (long)b * Ff * Ff;
    float invtr = 1.0f / scal[b];
#pragma unroll
    for (int i = 0; i < 2; ++i) {
#pragma unroll
        for (int j = 0; j < 4; ++j) {
            int n = nb + j * 16;
            float bm_n = mbar[bF + n], mv_n = mv[bF + n];
            float s4[4];
            unsigned short h4[4];
#pragma unroll
            for (int r = 0; r < 4; ++r) {
                int m = mb + i * 16 + r;
                float bm_m = mbar[bF + m], mv_m = mv[bF + m];
                float corr = 2048.0f * (bm_m * mv_n + mv_m * bm_n - mv_m * mv_n);
                float rc = rcov[(long)m * Ff + n];
                float d = (m == n) ? 1e-5f : 0.0f;
                float sig = 0.9f * rc + 0.1f * ((acc[i][j][r] - corr) * (1.0f / 2047.0f) + d);
                long idx = bS + (long)m * Ff + n;
                sig32[idx] = sig;
                unsigned short hh = f2bf(sig * invtr);
                S16[idx] = hh;
                s4[r] = sig; h4[r] = hh;
            }
            long midx = bS + (long)n * Ff + (mb + i * 16);
            *reinterpret_cast<float4*>(&sig32[midx]) =
                make_float4(s4[0], s4[1], s4[2], s4[3]);
            ushort4 hm; hm.x = h4[0]; hm.y = h4[1]; hm.z = h4[2]; hm.w = h4[3];
            *reinterpret_cast<ushort4*>(&S16[midx]) = hm;
        }
    }
}

// ---------------------------------------------------------------------------
// K3: BT-form GEMM, 2-phase double-buffered staging.
// MODE 2: pn = 1.5*aux32 - 0.5C -> out32, out16        (TRI)
// MODE 3: out = (C - vvec[n]) * rsqrt(tr) -> out32
// MODE 4: p1 = 1.5I - 0.5*aux32/tr; pn = 1.5p1-0.5C -> out32, out16  (TRI)
// MODE 6: sn=aux32/tr; T=2.25I-1.5sn+0.25C, U=1.5sn-0.5C (TRI)
// MODE 7: pn = 1.5*aux32 - 0.5C -> out16 only          (TRI)
// MODE 8: fused dual: out16 = bf16(A*Bt^T), out16b = bf16(A*B2^T)  (TRI)
// TRI: 20/32 triangle tiles; mirror writes for off-diagonal tiles; diagonal
//      128-blocks fully covered by primaries (mirrors skipped -> single-writer).
#define BK 32

template <int MODE, int BM, int BN, int MT, int NT, bool TRI>
__global__ __launch_bounds__(256, (MODE == 8 ? 3 : (BM * BN <= 8192 ? 4 : 3)))
void gemm_bt(
    const unsigned short* __restrict__ A, int lda, long strideA,
    const unsigned short* __restrict__ Bt, int ldb, long strideB,
    const unsigned short* __restrict__ B2, int K,
    const float* __restrict__ aux32,
    float* __restrict__ out32,
    unsigned short* __restrict__ out16,
    unsigned short* __restrict__ out16b,
    const float* __restrict__ vvec,
    float* __restrict__ scal,
    int ldc, long strideC) {
    constexpr bool FUSE = (MODE == 8);
    constexpr int AR = BM / 64, BR = BN / 64;
    constexpr int WM = BM / 2, WN = BN / 2;
    constexpr int MI = WM / 16, NJ = WN / 16;
    constexpr int ATOT = BM * BK, BTOT = BN * BK;
    constexpr int SZ = ATOT + BTOT + (FUSE ? BTOT : 0);
    __shared__ unsigned short sAll[2 * SZ];

    int lin = blockIdx.x;
    int b, m0, n0;
    if constexpr (TRI) {
        static_assert(BM == 128 && BN == 64, "TRI table assumes 128x64");
        int g = lin >> 3;
        b = (lin & 7) * 4 + g / 20;
        int kt = g % 20;
        int mi, nj;
        if      (kt < 8)  { mi = 0; nj = kt; }
        else if (kt < 14) { mi = 1; nj = kt - 6; }
        else if (kt < 18) { mi = 2; nj = kt - 10; }
        else              { mi = 3; nj = kt - 12; }
        m0 = mi * BM; n0 = nj * BN;
    } else {
        constexpr int NTILES = MT * NT;
        constexpr int TB = (NTILES == 16) ? 4 : ((NTILES == 32) ? 5 : 6);
        b = (lin & 7) * 4 + (lin >> (3 + TB));
        int tile = (lin >> 3) & (NTILES - 1);
        m0 = (tile & (MT - 1)) * BM;
        n0 = (tile / MT) * BN;
    }
    bool diag = false;
    if constexpr (TRI) diag = (m0 >> 7) == (n0 >> 7);

    int t = threadIdx.x;
    int w = t >> 6, l = t & 63;
    int wm = (w >> 1) * WM, wn = (w & 1) * WN;

    const unsigned short* gA = A + (long)b * strideA;
    const unsigned short* gB = Bt + (long)b * strideB;

    int srow = t >> 2, sk = (t & 3) * 8;
    const unsigned short* pa[AR];
    const unsigned short* pb[BR];
    const unsigned short* pb2[FUSE ? BR : 1];
#pragma unroll
    for (int r = 0; r < AR; ++r) pa[r] = gA + (long)(m0 + r * 64 + srow) * lda + sk;
#pragma unroll
    for (int r = 0; r < BR; ++r) pb[r] = gB + (long)(n0 + r * 64 + srow) * ldb + sk;
    if constexpr (FUSE) {
        const unsigned short* g2 = B2 + (long)b * strideB;
#pragma unroll
        for (int r = 0; r < BR; ++r)
            pb2[r] = g2 + (long)(n0 + r * 64 + srow) * ldb + sk;
    }

    int q = l >> 4, r16 = l & 15;
    int faOff = (wm + r16) * BK + q * 8;
    int fbOff = ATOT + (wn + r16) * BK + q * 8;
    int fb2Off = ATOT + BTOT + (wn + r16) * BK + q * 8;

    f32x4 acc[MI][NJ] = {};
    f32x4 acc2[FUSE ? MI : 1][FUSE ? NJ : 1] = {};

    auto stage = [&](int buf) {
        unsigned short* dA = &sAll[buf * SZ + t * 8];
#pragma unroll
        for (int r = 0; r < AR; ++r) { gload_lds16(pa[r], dA + r * 2048); pa[r] += BK; }
        unsigned short* dB = &sAll[buf * SZ + ATOT + t * 8];
#pragma unroll
        for (int r = 0; r < BR; ++r) { gload_lds16(pb[r], dB + r * 2048); pb[r] += BK; }
        if constexpr (FUSE) {
            unsigned short* dB2 = &sAll[buf * SZ + ATOT + BTOT + t * 8];
#pragma unroll
            for (int r = 0; r < BR; ++r) { gload_lds16(pb2[r], dB2 + r * 2048); pb2[r] += BK; }
        }
    };

    stage(0);
    __syncthreads();
    int cur = 0;
    for (int k0 = 0; k0 < K; k0 += BK) {
        if (k0 + BK < K) stage(cur ^ 1);
        const unsigned short* bufc = &sAll[cur * SZ];
        bf16x8 af[MI], bfr[NJ];
#pragma unroll
        for (int i = 0; i < MI; ++i)
            af[i] = *reinterpret_cast<const bf16x8*>(bufc + faOff + i * 16 * BK);
#pragma unroll
        for (int j = 0; j < NJ; ++j)
            bfr[j] = *reinterpret_cast<const bf16x8*>(bufc + fbOff + j * 16 * BK);
        if constexpr (FUSE) {
            bf16x8 bg[NJ];
#pragma unroll
            for (int j = 0; j < NJ; ++j)
                bg[j] = *reinterpret_cast<const bf16x8*>(bufc + fb2Off + j * 16 * BK);
#pragma unroll
            for (int i = 0; i < MI; ++i)
#pragma unroll
                for (int j = 0; j < NJ; ++j) {
                    acc[i][j] = __builtin_amdgcn_mfma_f32_16x16x32_bf16(
                        af[i], bfr[j], acc[i][j], 0, 0, 0);
                    acc2[i][j] = __builtin_amdgcn_mfma_f32_16x16x32_bf16(
                        af[i], bg[j], acc2[i][j], 0, 0, 0);
                }
        } else {
#pragma unroll
            for (int i = 0; i < MI; ++i)
#pragma unroll
                for (int j = 0; j < NJ; ++j)
                    acc[i][j] = __builtin_amdgcn_mfma_f32_16x16x32_bf16(
                        af[i], bfr[j], acc[i][j], 0, 0, 0);
        }
        __syncthreads();
        cur ^= 1;
    }

    // epilogue: C[row = wm+i*16+q*4+r][col = wn+j*16+r16]
    int mb = m0 + wm + q * 4;
    int nb = n0 + wn + r16;
    long bF = (long)b * Ff;
    long bC = (long)b * strideC;
    float rs = 0.f, invtr = 0.f;
    if constexpr (MODE == 3) rs = 1.0f / sqrtf(scal[b]);
    if constexpr (MODE == 4 || MODE == 6) invtr = 1.0f / scal[b];
#pragma unroll
    for (int i = 0; i < MI; ++i) {
#pragma unroll
        for (int j = 0; j < NJ; ++j) {
            int n = nb + j * 16;
            if constexpr (MODE == 6) {
                unsigned short tq[4], uq[4];
#pragma unroll
                for (int r = 0; r < 4; ++r) {
                    int m = mb + i * 16 + r;
                    long idx = bC + (long)m * ldc + n;
                    float v = acc[i][j][r];
                    float sn = aux32[idx] * invtr;
                    float dt = (m == n) ? 2.25f : 0.0f;
                    tq[r] = f2bf(dt - 1.5f * sn + 0.25f * v);
                    uq[r] = f2bf(1.5f * sn - 0.5f * v);
                    out16[idx] = tq[r];
                    out16b[idx] = uq[r];
                }
                if (TRI && !diag) {
                    long midx = bC + (long)n * ldc + (mb + i * 16);
                    ushort4 mt; mt.x = tq[0]; mt.y = tq[1]; mt.z = tq[2]; mt.w = tq[3];
                    ushort4 mu; mu.x = uq[0]; mu.y = uq[1]; mu.z = uq[2]; mu.w = uq[3];
                    *reinterpret_cast<ushort4*>(&out16[midx]) = mt;
                    *reinterpret_cast<ushort4*>(&out16b[midx]) = mu;
                }
            } else if constexpr (MODE == 2 || MODE == 4 || MODE == 7) {
                float p4[4];
                unsigned short h4[4];
#pragma unroll
                for (int r = 0; r < 4; ++r) {
                    int m = mb + i * 16 + r;
                    long idx = bC + (long)m * ldc + n;
                    float v = acc[i][j][r];
                    float pn;
                    if constexpr (MODE == 4) {
                        float p1 = ((m == n) ? 1.5f : 0.0f) - 0.5f * aux32[idx] * invtr;
                        pn = 1.5f * p1 - 0.5f * v;
                    } else {
                        pn = 1.5f * aux32[idx] - 0.5f * v;
                    }
                    unsigned short hh = f2bf(pn);
                    if constexpr (MODE != 7) out32[idx] = pn;
                    out16[idx] = hh;
                    p4[r] = pn; h4[r] = hh;
                }
                if (TRI && !diag) {
                    long midx = bC + (long)n * ldc + (mb + i * 16);
                    if constexpr (MODE != 7)
                        *reinterpret_cast<float4*>(&out32[midx]) =
                            make_float4(p4[0], p4[1], p4[2], p4[3]);
                    ushort4 hm; hm.x = h4[0]; hm.y = h4[1]; hm.z = h4[2]; hm.w = h4[3];
                    *reinterpret_cast<ushort4*>(&out16[midx]) = hm;
                }
            } else if constexpr (MODE == 8) {
                unsigned short h4[4], g4[4];
#pragma unroll
                for (int r = 0; r < 4; ++r) {
                    int m = mb + i * 16 + r;
                    long idx = bC + (long)m * ldc + n;
                    h4[r] = f2bf(acc[i][j][r]);
                    g4[r] = f2bf(acc2[i][j][r]);
                    out16[idx] = h4[r];
                    out16b[idx] = g4[r];
                }
                if (TRI && !diag) {
                    long midx = bC + (long)n * ldc + (mb + i * 16);
                    ushort4 hm; hm.x = h4[0]; hm.y = h4[1]; hm.z = h4[2]; hm.w = h4[3];
                    ushort4 gm; gm.x = g4[0]; gm.y = g4[1]; gm.z = g4[2]; gm.w = g4[3];
                    *reinterpret_cast<ushort4*>(&out16[midx]) = hm;
                    *reinterpret_cast<ushort4*>(&out16b[midx]) = gm;
                }
            } else {
#pragma unroll
                for (int r = 0; r < 4; ++r) {
                    int m = mb + i * 16 + r;
                    long idx = bC + (long)m * ldc + n;
                    float v = acc[i][j][r];
                    if constexpr (MODE == 3) {
                        out32[idx] = (v - vvec[bF + n]) * rs;
                    } else {
                        out32[idx] = v;
                    }
                }
            }
        }
    }
}

// ---------------------------------------------------------------------------
// K6: vvec[b][n] = sum_k mv[b][k] * P16[b][k][n]
__global__ __launch_bounds__(256) void mvecp(
    const float* __restrict__ mv, const unsigned short* __restrict__ P16,
    float* __restrict__ vvec) {
    int b = blockIdx.x;
    int n = blockIdx.y * 256 + threadIdx.x;
    const unsigned short* P = P16 + (long)b * Ff * Ff + n;
    const float* m = mv + (long)b * Ff;
    float a0 = 0.f, a1 = 0.f, a2 = 0.f, a3 = 0.f;
    for (int k = 0; k < Ff; k += 4) {
        a0 += m[k]     * bf2f(P[(long)k * Ff]);
        a1 += m[k + 1] * bf2f(P[(long)(k + 1) * Ff]);
        a2 += m[k + 2] * bf2f(P[(long)(k + 2) * Ff]);
        a3 += m[k + 3] * bf2f(P[(long)(k + 3) * Ff]);
    }
    vvec[(long)b * Ff + n] = (a0 + a1) + (a2 + a3);
}

// ---------------------------------------------------------------------------
extern "C" void kernel_launch(void* const* d_in, const int* in_sizes, int n_in,
                              void* d_out, int out_size, void* d_ws, size_t ws_size,
                              hipStream_t stream) {
    const float* x    = (const float*)d_in[0];
    const float* rm   = (const float*)d_in[1];
    const float* rcov = (const float*)d_in[2];
    float* out = (float*)d_out;

    char* ws = (char*)d_ws;
    unsigned short* x16   = (unsigned short*)(ws);                 // 64 MB
    float*          P32b  = (float*)(ws + 67108864L);              // 32 MB
    float*          sig32 = (float*)(ws + 134217728L);             // 32 MB
    float*          P32a  = (float*)(ws + 167772160L);             // 32 MB
    unsigned short* S16   = (unsigned short*)(ws + 201326592L);    // 16 MB
    unsigned short* P16   = (unsigned short*)(ws + 218103808L);    // 16 MB
    unsigned short* T16   = (unsigned short*)(ws + 234881024L);    // 16 MB
    unsigned short* U16   = (unsigned short*)(ws + 251658240L);    // 16 MB
    float*          msum_p= (float*)(ws + 268435456L);             // 2 MB
    float*          mbar  = (float*)(ws + 270532608L);             // 64 KB
    float*          mv    = (float*)(ws + 270598144L);             // 64 KB
    float*          vvec  = (float*)(ws + 270663680L);             // 64 KB
    float*          scal  = (float*)(ws + 270729216L);             // 128 B
    float*          msumsq_p = (float*)d_out;  // 2 MB scratch, overwritten by final

    const long sFF = (long)Ff * Ff;
    const long sSF = (long)Ss * Ff;

    cast_colsum<<<dim3(32, Bb), 256, 0, stream>>>(x, x16, msum_p, msumsq_p);
    meanred<<<Bb, 256, 0, stream>>>(msum_p, msumsq_p, rm, rcov, mbar, mv, scal);

    // sigma + S16, TN-form from x16, triangle + mirror
    gram_tn<<<640, 256, 0, stream>>>(x16, rcov, mbar, mv, scal, sig32, S16);

    // G1: W = sn^2 -> T,U (TRI)
    gemm_bt<6, 128, 64, 4, 8, true><<<640, 256, 0, stream>>>(
        S16, Ff, sFF, S16, Ff, sFF, nullptr, Ff,
        sig32, nullptr, T16, U16, nullptr, scal, Ff, sFF);
    // G2: P2 = 1.5 P1 - 0.5 T*U -> P32a, P16 (TRI)
    gemm_bt<4, 128, 64, 4, 8, true><<<640, 256, 0, stream>>>(
        T16, Ff, sFF, U16, Ff, sFF, nullptr, Ff,
        sig32, P32a, P16, nullptr, nullptr, scal, Ff, sFF);

    // iter 3: fused dual {T=P^2, U=P*sn} (TRI); P3 = 1.5*P32a - 0.5 T*U -> P32b
    gemm_bt<8, 128, 64, 4, 8, true><<<640, 256, 0, stream>>>(
        P16, Ff, sFF, P16, Ff, sFF, S16, Ff,
        nullptr, nullptr, T16, U16, nullptr, nullptr, Ff, sFF);
    gemm_bt<2, 128, 64, 4, 8, true><<<640, 256, 0, stream>>>(
        T16, Ff, sFF, U16, Ff, sFF, nullptr, Ff,
        P32a, P32b, P16, nullptr, nullptr, nullptr, Ff, sFF);
    // iter 4: fused dual (TRI); P4 = 1.5*P32b - 0.5 T*U -> P16 only
    gemm_bt<8, 128, 64, 4, 8, true><<<640, 256, 0, stream>>>(
        P16, Ff, sFF, P16, Ff, sFF, S16, Ff,
        nullptr, nullptr, T16, U16, nullptr, nullptr, Ff, sFF);
    gemm_bt<7, 128, 64, 4, 8, true><<<640, 256, 0, stream>>>(
        T16, Ff, sFF, U16, Ff, sFF, nullptr, Ff,
        P32b, nullptr, P16, nullptr, nullptr, nullptr, Ff, sFF);

    mvecp<<<dim3(Bb, 2), 256, 0, stream>>>(mv, P16, vvec);

    // out = (x@P4 - mv@P4) * tr^{-1/2}
    gemm_bt<3, 128, 128, 16, 4, false><<<2048, 256, 0, stream>>>(
        x16, Ff, sSF, P16, Ff, sFF, nullptr, Ff,
        nullptr, out, nullptr, nullptr, vvec, scal, Ff, sSF);
}

// Round 5
// 498.477 us; speedup vs baseline: 1.1740x; 1.0075x over previous
//
#include <hip/hip_runtime.h>

// ---------------------------------------------------------------------------
// Whitening2d: B=32, S=2048, F=512, fp32 in/out.
//   K1 (cast_colsum): streaming x -> x16 (bf16) + col sums/sumsq. No transpose.
//   K2 (meanred): mbar, mv, trace(sigma) -> scal[b]
//   gram_tn: sigma = 0.9 rcov + 0.1((x^T x - corr)/2047 + eps I), S16 = sigma/tr
//            TN-form from row-major x16 via ds_read_b64_tr_b16 fragments.
//            Triangle tiles (exact symmetry) + mirrored writes.
//   ALL NS-chain products are symmetric -> 20/32 triangle tiles + mirrors
//   (mirrors skipped on diagonal 128-blocks -> single-writer, deterministic).
//   G1 (MODE 6, TRI): W = sn^2 -> T,U
//   G2 (MODE 4, TRI): P2 = 1.5 P1 - 0.5 T*U -> P32a, P16
//   iter 3: MODE 8 TRI dual {T=P^2, U=P*sn}; MODE 2 TRI -> P32b, P16
//   iter 4: MODE 8 TRI dual; MODE 7 TRI -> P16 only
//   final (MODE 3): out = (x@P4 - mv@P4) * tr^{-1/2}
//   All GEMM K-loops: counted-vmcnt double-buffer schedule (T3/T4):
//     stage(next) -> s_waitcnt vmcnt(NL) [waits loads issued a FULL step ago]
//     -> raw s_barrier -> ds_read/MFMA -> raw s_barrier.  No vmcnt(0) drain
//     in the main loop (the __syncthreads drain was the dominant per-step
//     stall: ~16 K-steps x ~200cy exposed latency).
// ---------------------------------------------------------------------------

#define Bb 32
#define Ss 2048
#define Ff 512

typedef __attribute__((ext_vector_type(8))) short bf16x8;
typedef __attribute__((ext_vector_type(4))) short bf16x4;
typedef __attribute__((ext_vector_type(8))) short short8;
typedef __attribute__((ext_vector_type(4))) float f32x4;

__device__ __forceinline__ unsigned short f2bf(float f) {
    unsigned int u = __float_as_uint(f);
    u += 0x7fffu + ((u >> 16) & 1u);   // RTNE
    return (unsigned short)(u >> 16);
}
__device__ __forceinline__ float bf2f(unsigned short u) {
    return __uint_as_float(((unsigned int)u) << 16);
}

__device__ __forceinline__ void gload_lds16(const void* g, void* l) {
    __builtin_amdgcn_global_load_lds(
        (const __attribute__((address_space(1))) void*)g,
        (__attribute__((address_space(3))) void*)l,
        16, 0, 0);
}

// ds_read_b64_tr_b16: per-lane gather of 4 bf16 at +0,+32,+64,+96 bytes.
// Two reads (offset 0 / 128B) give k = q*8+0..7 from [32s][16f] subtiles.
__device__ __forceinline__ bf16x8 tr_read(unsigned addr) {
    bf16x4 lo, hi;
    asm volatile("ds_read_b64_tr_b16 %0, %2\n\t"
                 "ds_read_b64_tr_b16 %1, %2 offset:128"
                 : "=&v"(lo), "=&v"(hi)
                 : "v"(addr));
    return __builtin_shufflevector(lo, hi, 0, 1, 2, 3, 4, 5, 6, 7);
}

// ---------------------------------------------------------------------------
// K1: pure streaming: x -> x16, col-sums + col-sumsq partials.
__global__ __launch_bounds__(256) void cast_colsum(
    const float* __restrict__ x, unsigned short* __restrict__ x16,
    float* __restrict__ msum_p, float* __restrict__ msumsq_p) {
    __shared__ float redm[4 * 512];
    __shared__ float redq[4 * 512];
    int b = blockIdx.y, sc = blockIdx.x;
    int t = threadIdx.x;
    int fi = t & 63, wr = t >> 6;
    long base = ((long)b * Ss + sc * 64 + wr) * Ff + fi * 8;
    const float* px = x + base;
    unsigned short* p16 = x16 + base;
    float sm[8] = {0.f, 0.f, 0.f, 0.f, 0.f, 0.f, 0.f, 0.f};
    float sq[8] = {0.f, 0.f, 0.f, 0.f, 0.f, 0.f, 0.f, 0.f};
#pragma unroll 4
    for (int i = 0; i < 16; ++i) {
        const float* p = px + (long)i * 4 * Ff;
        float4 v0 = *reinterpret_cast<const float4*>(p);
        float4 v1 = *reinterpret_cast<const float4*>(p + 4);
        short8 hv;
        hv[0] = (short)f2bf(v0.x); hv[1] = (short)f2bf(v0.y);
        hv[2] = (short)f2bf(v0.z); hv[3] = (short)f2bf(v0.w);
        hv[4] = (short)f2bf(v1.x); hv[5] = (short)f2bf(v1.y);
        hv[6] = (short)f2bf(v1.z); hv[7] = (short)f2bf(v1.w);
        *reinterpret_cast<short8*>(p16 + (long)i * 4 * Ff) = hv;
        sm[0] += v0.x; sq[0] += v0.x * v0.x;
        sm[1] += v0.y; sq[1] += v0.y * v0.y;
        sm[2] += v0.z; sq[2] += v0.z * v0.z;
        sm[3] += v0.w; sq[3] += v0.w * v0.w;
        sm[4] += v1.x; sq[4] += v1.x * v1.x;
        sm[5] += v1.y; sq[5] += v1.y * v1.y;
        sm[6] += v1.z; sq[6] += v1.z * v1.z;
        sm[7] += v1.w; sq[7] += v1.w * v1.w;
    }
#pragma unroll
    for (int e = 0; e < 8; ++e) {
        int idx = e * 64 + (fi ^ (e << 3));
        redm[wr * 512 + idx] = sm[e];
        redq[wr * 512 + idx] = sq[e];
    }
    __syncthreads();
#pragma unroll
    for (int h = 0; h < 2; ++h) {
        int f = t + h * 256;
        int e = f & 7, a = f >> 3;
        int idx = e * 64 + (a ^ (e << 3));
        float s = (redm[idx] + redm[512 + idx]) + (redm[1024 + idx] + redm[1536 + idx]);
        float qq = (redq[idx] + redq[512 + idx]) + (redq[1024 + idx] + redq[1536 + idx]);
        msum_p[((long)b * 32 + sc) * Ff + f] = s;
        msumsq_p[((long)b * 32 + sc) * Ff + f] = qq;
    }
}

// ---------------------------------------------------------------------------
// K2: reduce partials -> mbar, mv, trace(sigma) -> scal[b]
__global__ __launch_bounds__(256) void meanred(
    const float* __restrict__ msum_p, const float* __restrict__ msumsq_p,
    const float* __restrict__ rm, const float* __restrict__ rcov,
    float* __restrict__ mbar, float* __restrict__ mv,
    float* __restrict__ scal) {
    int b = blockIdx.x, t = threadIdx.x;
    float tp = 0.f;
#pragma unroll
    for (int h = 0; h < 2; ++h) {
        int f = t + h * 256;
        float s = 0.f, q = 0.f;
#pragma unroll 8
        for (int st = 0; st < 32; ++st) {
            s += msum_p[((long)b * 32 + st) * Ff + f];
            q += msumsq_p[((long)b * 32 + st) * Ff + f];
        }
        float mb_ = s * (1.0f / 2048.0f);
        float mvv = 0.9f * rm[f] + 0.1f * mb_;
        mbar[b * Ff + f] = mb_;
        mv[b * Ff + f] = mvv;
        float corr = 2048.0f * (2.0f * mb_ * mvv - mvv * mvv);
        float rc = rcov[(long)f * Ff + f];
        tp += 0.9f * rc + 0.1f * ((q - corr) * (1.0f / 2047.0f) + 1e-5f);
    }
    __shared__ float red[4];
#pragma unroll
    for (int off = 32; off; off >>= 1) tp += __shfl_down(tp, off, 64);
    if ((t & 63) == 0) red[t >> 6] = tp;
    __syncthreads();
    if (t == 0) scal[b] = (red[0] + red[1]) + (red[2] + red[3]);
}

// ---------------------------------------------------------------------------
// Sigma: TN Gram from row-major x16. 64x128 tiles, triangle (20/32) + mirror.
// Counted-vmcnt dbuf: NL=3 loads/step; wait only loads issued one step ago.
__global__ __launch_bounds__(256, 2) void gram_tn(
    const unsigned short* __restrict__ x16,
    const float* __restrict__ rcov,
    const float* __restrict__ mbar, const float* __restrict__ mv,
    const float* __restrict__ scal,
    float* __restrict__ sig32, unsigned short* __restrict__ S16) {
    constexpr int SZ = 6144;               // ushorts per buffer
    __shared__ unsigned short sAll[2 * SZ];
    int lin = blockIdx.x;
    int g = lin >> 3;
    int b = (lin & 7) * 4 + g / 20;
    int kt = g % 20;
    int mi, nj;
    if      (kt < 4)  { mi = 0; nj = kt; }
    else if (kt < 8)  { mi = 1; nj = kt - 4; }
    else if (kt < 11) { mi = 2; nj = kt - 7; }
    else if (kt < 14) { mi = 3; nj = kt - 10; }
    else if (kt < 16) { mi = 4; nj = kt - 12; }
    else if (kt < 18) { mi = 5; nj = kt - 14; }
    else if (kt < 19) { mi = 6; nj = 3; }
    else              { mi = 7; nj = 3; }
    int m0 = mi * 64, n0 = nj * 128;

    int t = threadIdx.x;
    int w = t >> 6, l = t & 63;
    int wm = (w >> 1) * 32, wn = (w & 1) * 64;
    int q = l >> 4, r16 = l & 15;

    const unsigned short* gx = x16 + (long)b * Ss * Ff;
    int s_ld = (t >> 1) & 31;
    int aoff = m0 + (t >> 6) * 16 + (t & 1) * 8;
    int boff = n0 + (t >> 6) * 16 + (t & 1) * 8;
    const unsigned short* srow = gx + (long)s_ld * Ff;

    f32x4 acc[2][4] = {};
    unsigned aB = (unsigned)(unsigned long long)
        &sAll[((w >> 1) * 2) * 512 + q * 128 + r16];
    unsigned bB = (unsigned)(unsigned long long)
        &sAll[2048 + ((w & 1) * 4) * 512 + q * 128 + r16];

    {
        unsigned short* d0 = &sAll[t * 8];
        gload_lds16(srow + aoff, d0);
        gload_lds16(srow + boff, d0 + 2048);
        gload_lds16(srow + boff + 64, d0 + 4096);
    }
    asm volatile("s_waitcnt vmcnt(0)" ::: "memory");
    __builtin_amdgcn_s_barrier();

    int cur = 0;
    for (int k0 = 0; k0 < Ss; k0 += 32) {
        if (k0 + 32 < Ss) {
            const unsigned short* sr = srow + (long)(k0 + 32) * Ff;
            unsigned short* dd = &sAll[(cur ^ 1) * SZ + t * 8];
            gload_lds16(sr + aoff, dd);
            gload_lds16(sr + boff, dd + 2048);
            gload_lds16(sr + boff + 64, dd + 4096);
            asm volatile("s_waitcnt vmcnt(3)" ::: "memory");
        } else {
            asm volatile("s_waitcnt vmcnt(0)" ::: "memory");
        }
        __builtin_amdgcn_s_barrier();
        __builtin_amdgcn_sched_barrier(0);
        unsigned ab = aB + (unsigned)(cur * (SZ * 2));
        unsigned bb = bB + (unsigned)(cur * (SZ * 2));
        bf16x8 a0 = tr_read(ab);
        bf16x8 a1 = tr_read(ab + 1024);
        bf16x8 b0 = tr_read(bb);
        bf16x8 b1 = tr_read(bb + 1024);
        bf16x8 b2 = tr_read(bb + 2048);
        bf16x8 b3 = tr_read(bb + 3072);
        asm volatile("s_waitcnt lgkmcnt(0)" ::: "memory");
        __builtin_amdgcn_sched_barrier(0);
        acc[0][0] = __builtin_amdgcn_mfma_f32_16x16x32_bf16(a0, b0, acc[0][0], 0, 0, 0);
        acc[0][1] = __builtin_amdgcn_mfma_f32_16x16x32_bf16(a0, b1, acc[0][1], 0, 0, 0);
        acc[0][2] = __builtin_amdgcn_mfma_f32_16x16x32_bf16(a0, b2, acc[0][2], 0, 0, 0);
        acc[0][3] = __builtin_amdgcn_mfma_f32_16x16x32_bf16(a0, b3, acc[0][3], 0, 0, 0);
        acc[1][0] = __builtin_amdgcn_mfma_f32_16x16x32_bf16(a1, b0, acc[1][0], 0, 0, 0);
        acc[1][1] = __builtin_amdgcn_mfma_f32_16x16x32_bf16(a1, b1, acc[1][1], 0, 0, 0);
        acc[1][2] = __builtin_amdgcn_mfma_f32_16x16x32_bf16(a1, b2, acc[1][2], 0, 0, 0);
        acc[1][3] = __builtin_amdgcn_mfma_f32_16x16x32_bf16(a1, b3, acc[1][3], 0, 0, 0);
        __builtin_amdgcn_s_barrier();
        cur ^= 1;
    }

    int mb = m0 + wm + q * 4;
    int nb = n0 + wn + r16;
    long bF = (long)b * Ff;
    long bS = (long)b * Ff * Ff;
    float invtr = 1.0f / scal[b];
#pragma unroll
    for (int i = 0; i < 2; ++i) {
#pragma unroll
        for (int j = 0; j < 4; ++j) {
            int n = nb + j * 16;
            float bm_n = mbar[bF + n], mv_n = mv[bF + n];
            float s4[4];
            unsigned short h4[4];
#pragma unroll
            for (int r = 0; r < 4; ++r) {
                int m = mb + i * 16 + r;
                float bm_m = mbar[bF + m], mv_m = mv[bF + m];
                float corr = 2048.0f * (bm_m * mv_n + mv_m * bm_n - mv_m * mv_n);
                float rc = rcov[(long)m * Ff + n];
                float d = (m == n) ? 1e-5f : 0.0f;
                float sig = 0.9f * rc + 0.1f * ((acc[i][j][r] - corr) * (1.0f / 2047.0f) + d);
                long idx = bS + (long)m * Ff + n;
                sig32[idx] = sig;
                unsigned short hh = f2bf(sig * invtr);
                S16[idx] = hh;
                s4[r] = sig; h4[r] = hh;
            }
            long midx = bS + (long)n * Ff + (mb + i * 16);
            *reinterpret_cast<float4*>(&sig32[midx]) =
                make_float4(s4[0], s4[1], s4[2], s4[3]);
            ushort4 hm; hm.x = h4[0]; hm.y = h4[1]; hm.z = h4[2]; hm.w = h4[3];
            *reinterpret_cast<ushort4*>(&S16[midx]) = hm;
        }
    }
}

// ---------------------------------------------------------------------------
// K3: BT-form GEMM, counted-vmcnt double-buffered staging.
// MODE 2: pn = 1.5*aux32 - 0.5C -> out32, out16        (TRI)
// MODE 3: out = (C - vvec[n]) * rsqrt(tr) -> out32
// MODE 4: p1 = 1.5I - 0.5*aux32/tr; pn = 1.5p1-0.5C -> out32, out16  (TRI)
// MODE 6: sn=aux32/tr; T=2.25I-1.5sn+0.25C, U=1.5sn-0.5C (TRI)
// MODE 7: pn = 1.5*aux32 - 0.5C -> out16 only          (TRI)
// MODE 8: fused dual: out16 = bf16(A*Bt^T), out16b = bf16(A*B2^T)  (TRI)
#define BK 32

template <int MODE, int BM, int BN, int MT, int NT, bool TRI>
__global__ __launch_bounds__(256, (MODE == 8 ? 3 : (BM * BN <= 8192 ? 4 : 3)))
void gemm_bt(
    const unsigned short* __restrict__ A, int lda, long strideA,
    const unsigned short* __restrict__ Bt, int ldb, long strideB,
    const unsigned short* __restrict__ B2, int K,
    const float* __restrict__ aux32,
    float* __restrict__ out32,
    unsigned short* __restrict__ out16,
    unsigned short* __restrict__ out16b,
    const float* __restrict__ vvec,
    float* __restrict__ scal,
    int ldc, long strideC) {
    constexpr bool FUSE = (MODE == 8);
    constexpr int AR = BM / 64, BR = BN / 64;
    constexpr int WM = BM / 2, WN = BN / 2;
    constexpr int MI = WM / 16, NJ = WN / 16;
    constexpr int ATOT = BM * BK, BTOT = BN * BK;
    constexpr int SZ = ATOT + BTOT + (FUSE ? BTOT : 0);
    constexpr int NL = AR + BR + (FUSE ? BR : 0);   // gload_lds per thread/step
    __shared__ unsigned short sAll[2 * SZ];

    int lin = blockIdx.x;
    int b, m0, n0;
    if constexpr (TRI) {
        static_assert(BM == 128 && BN == 64, "TRI table assumes 128x64");
        int g = lin >> 3;
        b = (lin & 7) * 4 + g / 20;
        int kt = g % 20;
        int mi, nj;
        if      (kt < 8)  { mi = 0; nj = kt; }
        else if (kt < 14) { mi = 1; nj = kt - 6; }
        else if (kt < 18) { mi = 2; nj = kt - 10; }
        else              { mi = 3; nj = kt - 12; }
        m0 = mi * BM; n0 = nj * BN;
    } else {
        constexpr int NTILES = MT * NT;
        constexpr int TB = (NTILES == 16) ? 4 : ((NTILES == 32) ? 5 : 6);
        b = (lin & 7) * 4 + (lin >> (3 + TB));
        int tile = (lin >> 3) & (NTILES - 1);
        m0 = (tile & (MT - 1)) * BM;
        n0 = (tile / MT) * BN;
    }
    bool diag = false;
    if constexpr (TRI) diag = (m0 >> 7) == (n0 >> 7);

    int t = threadIdx.x;
    int w = t >> 6, l = t & 63;
    int wm = (w >> 1) * WM, wn = (w & 1) * WN;

    const unsigned short* gA = A + (long)b * strideA;
    const unsigned short* gB = Bt + (long)b * strideB;

    int srow = t >> 2, sk = (t & 3) * 8;
    const unsigned short* pa[AR];
    const unsigned short* pb[BR];
    const unsigned short* pb2[FUSE ? BR : 1];
#pragma unroll
    for (int r = 0; r < AR; ++r) pa[r] = gA + (long)(m0 + r * 64 + srow) * lda + sk;
#pragma unroll
    for (int r = 0; r < BR; ++r) pb[r] = gB + (long)(n0 + r * 64 + srow) * ldb + sk;
    if constexpr (FUSE) {
        const unsigned short* g2 = B2 + (long)b * strideB;
#pragma unroll
        for (int r = 0; r < BR; ++r)
            pb2[r] = g2 + (long)(n0 + r * 64 + srow) * ldb + sk;
    }

    int q = l >> 4, r16 = l & 15;
    int faOff = (wm + r16) * BK + q * 8;
    int fbOff = ATOT + (wn + r16) * BK + q * 8;
    int fb2Off = ATOT + BTOT + (wn + r16) * BK + q * 8;

    f32x4 acc[MI][NJ] = {};
    f32x4 acc2[FUSE ? MI : 1][FUSE ? NJ : 1] = {};

    auto stage = [&](int buf) {
        unsigned short* dA = &sAll[buf * SZ + t * 8];
#pragma unroll
        for (int r = 0; r < AR; ++r) { gload_lds16(pa[r], dA + r * 2048); pa[r] += BK; }
        unsigned short* dB = &sAll[buf * SZ + ATOT + t * 8];
#pragma unroll
        for (int r = 0; r < BR; ++r) { gload_lds16(pb[r], dB + r * 2048); pb[r] += BK; }
        if constexpr (FUSE) {
            unsigned short* dB2 = &sAll[buf * SZ + ATOT + BTOT + t * 8];
#pragma unroll
            for (int r = 0; r < BR; ++r) { gload_lds16(pb2[r], dB2 + r * 2048); pb2[r] += BK; }
        }
    };

    stage(0);
    asm volatile("s_waitcnt vmcnt(0)" ::: "memory");
    __builtin_amdgcn_s_barrier();
    int cur = 0;
    for (int k0 = 0; k0 < K; k0 += BK) {
        if (k0 + BK < K) {
            stage(cur ^ 1);
            asm volatile("s_waitcnt vmcnt(%0)" :: "i"(NL) : "memory");
        } else {
            asm volatile("s_waitcnt vmcnt(0)" ::: "memory");
        }
        __builtin_amdgcn_s_barrier();
        __builtin_amdgcn_sched_barrier(0);
        const unsigned short* bufc = &sAll[cur * SZ];
        bf16x8 af[MI], bfr[NJ];
#pragma unroll
        for (int i = 0; i < MI; ++i)
            af[i] = *reinterpret_cast<const bf16x8*>(bufc + faOff + i * 16 * BK);
#pragma unroll
        for (int j = 0; j < NJ; ++j)
            bfr[j] = *reinterpret_cast<const bf16x8*>(bufc + fbOff + j * 16 * BK);
        if constexpr (FUSE) {
            bf16x8 bg[NJ];
#pragma unroll
            for (int j = 0; j < NJ; ++j)
                bg[j] = *reinterpret_cast<const bf16x8*>(bufc + fb2Off + j * 16 * BK);
#pragma unroll
            for (int i = 0; i < MI; ++i)
#pragma unroll
                for (int j = 0; j < NJ; ++j) {
                    acc[i][j] = __builtin_amdgcn_mfma_f32_16x16x32_bf16(
                        af[i], bfr[j], acc[i][j], 0, 0, 0);
                    acc2[i][j] = __builtin_amdgcn_mfma_f32_16x16x32_bf16(
                        af[i], bg[j], acc2[i][j], 0, 0, 0);
                }
        } else {
#pragma unroll
            for (int i = 0; i < MI; ++i)
#pragma unroll
                for (int j = 0; j < NJ; ++j)
                    acc[i][j] = __builtin_amdgcn_mfma_f32_16x16x32_bf16(
                        af[i], bfr[j], acc[i][j], 0, 0, 0);
        }
        __builtin_amdgcn_s_barrier();
        cur ^= 1;
    }

    // epilogue: C[row = wm+i*16+q*4+r][col = wn+j*16+r16]
    int mb = m0 + wm + q * 4;
    int nb = n0 + wn + r16;
    long bF = (long)b * Ff;
    long bC = (long)b * strideC;
    float rs = 0.f, invtr = 0.f;
    if constexpr (MODE == 3) rs = 1.0f / sqrtf(scal[b]);
    if constexpr (MODE == 4 || MODE == 6) invtr = 1.0f / scal[b];
#pragma unroll
    for (int i = 0; i < MI; ++i) {
#pragma unroll
        for (int j = 0; j < NJ; ++j) {
            int n = nb + j * 16;
            if constexpr (MODE == 6) {
                unsigned short tq[4], uq[4];
#pragma unroll
                for (int r = 0; r < 4; ++r) {
                    int m = mb + i * 16 + r;
                    long idx = bC + (long)m * ldc + n;
                    float v = acc[i][j][r];
                    float sn = aux32[idx] * invtr;
                    float dt = (m == n) ? 2.25f : 0.0f;
                    tq[r] = f2bf(dt - 1.5f * sn + 0.25f * v);
                    uq[r] = f2bf(1.5f * sn - 0.5f * v);
                    out16[idx] = tq[r];
                    out16b[idx] = uq[r];
                }
                if (TRI && !diag) {
                    long midx = bC + (long)n * ldc + (mb + i * 16);
                    ushort4 mt; mt.x = tq[0]; mt.y = tq[1]; mt.z = tq[2]; mt.w = tq[3];
                    ushort4 mu; mu.x = uq[0]; mu.y = uq[1]; mu.z = uq[2]; mu.w = uq[3];
                    *reinterpret_cast<ushort4*>(&out16[midx]) = mt;
                    *reinterpret_cast<ushort4*>(&out16b[midx]) = mu;
                }
            } else if constexpr (MODE == 2 || MODE == 4 || MODE == 7) {
                float p4[4];
                unsigned short h4[4];
#pragma unroll
                for (int r = 0; r < 4; ++r) {
                    int m = mb + i * 16 + r;
                    long idx = bC + (long)m * ldc + n;
                    float v = acc[i][j][r];
                    float pn;
                    if constexpr (MODE == 4) {
                        float p1 = ((m == n) ? 1.5f : 0.0f) - 0.5f * aux32[idx] * invtr;
                        pn = 1.5f * p1 - 0.5f * v;
                    } else {
                        pn = 1.5f * aux32[idx] - 0.5f * v;
                    }
                    unsigned short hh = f2bf(pn);
                    if constexpr (MODE != 7) out32[idx] = pn;
                    out16[idx] = hh;
                    p4[r] = pn; h4[r] = hh;
                }
                if (TRI && !diag) {
                    long midx = bC + (long)n * ldc + (mb + i * 16);
                    if constexpr (MODE != 7)
                        *reinterpret_cast<float4*>(&out32[midx]) =
                            make_float4(p4[0], p4[1], p4[2], p4[3]);
                    ushort4 hm; hm.x = h4[0]; hm.y = h4[1]; hm.z = h4[2]; hm.w = h4[3];
                    *reinterpret_cast<ushort4*>(&out16[midx]) = hm;
                }
            } else if constexpr (MODE == 8) {
                unsigned short h4[4], g4[4];
#pragma unroll
                for (int r = 0; r < 4; ++r) {
                    int m = mb + i * 16 + r;
                    long idx = bC + (long)m * ldc + n;
                    h4[r] = f2bf(acc[i][j][r]);
                    g4[r] = f2bf(acc2[i][j][r]);
                    out16[idx] = h4[r];
                    out16b[idx] = g4[r];
                }
                if (TRI && !diag) {
                    long midx = bC + (long)n * ldc + (mb + i * 16);
                    ushort4 hm; hm.x = h4[0]; hm.y = h4[1]; hm.z = h4[2]; hm.w = h4[3];
                    ushort4 gm; gm.x = g4[0]; gm.y = g4[1]; gm.z = g4[2]; gm.w = g4[3];
                    *reinterpret_cast<ushort4*>(&out16[midx]) = hm;
                    *reinterpret_cast<ushort4*>(&out16b[midx]) = gm;
                }
            } else {
#pragma unroll
                for (int r = 0; r < 4; ++r) {
                    int m = mb + i * 16 + r;
                    long idx = bC + (long)m * ldc + n;
                    float v = acc[i][j][r];
                    if constexpr (MODE == 3) {
                        out32[idx] = (v - vvec[bF + n]) * rs;
                    } else {
                        out32[idx] = v;
                    }
                }
            }
        }
    }
}

// ---------------------------------------------------------------------------
// K6: vvec[b][n] = sum_k mv[b][k] * P16[b][k][n]
__global__ __launch_bounds__(256) void mvecp(
    const float* __restrict__ mv, const unsigned short* __restrict__ P16,
    float* __restrict__ vvec) {
    int b = blockIdx.x;
    int n = blockIdx.y * 256 + threadIdx.x;
    const unsigned short* P = P16 + (long)b * Ff * Ff + n;
    const float* m = mv + (long)b * Ff;
    float a0 = 0.f, a1 = 0.f, a2 = 0.f, a3 = 0.f;
    for (int k = 0; k < Ff; k += 4) {
        a0 += m[k]     * bf2f(P[(long)k * Ff]);
        a1 += m[k + 1] * bf2f(P[(long)(k + 1) * Ff]);
        a2 += m[k + 2] * bf2f(P[(long)(k + 2) * Ff]);
        a3 += m[k + 3] * bf2f(P[(long)(k + 3) * Ff]);
    }
    vvec[(long)b * Ff + n] = (a0 + a1) + (a2 + a3);
}

// ---------------------------------------------------------------------------
extern "C" void kernel_launch(void* const* d_in, const int* in_sizes, int n_in,
                              void* d_out, int out_size, void* d_ws, size_t ws_size,
                              hipStream_t stream) {
    const float* x    = (const float*)d_in[0];
    const float* rm   = (const float*)d_in[1];
    const float* rcov = (const float*)d_in[2];
    float* out = (float*)d_out;

    char* ws = (char*)d_ws;
    unsigned short* x16   = (unsigned short*)(ws);                 // 64 MB
    float*          P32b  = (float*)(ws + 67108864L);              // 32 MB
    float*          sig32 = (float*)(ws + 134217728L);             // 32 MB
    float*          P32a  = (float*)(ws + 167772160L);             // 32 MB
    unsigned short* S16   = (unsigned short*)(ws + 201326592L);    // 16 MB
    unsigned short* P16   = (unsigned short*)(ws + 218103808L);    // 16 MB
    unsigned short* T16   = (unsigned short*)(ws + 234881024L);    // 16 MB
    unsigned short* U16   = (unsigned short*)(ws + 251658240L);    // 16 MB
    float*          msum_p= (float*)(ws + 268435456L);             // 2 MB
    float*          mbar  = (float*)(ws + 270532608L);             // 64 KB
    float*          mv    = (float*)(ws + 270598144L);             // 64 KB
    float*          vvec  = (float*)(ws + 270663680L);             // 64 KB
    float*          scal  = (float*)(ws + 270729216L);             // 128 B
    float*          msumsq_p = (float*)d_out;  // 2 MB scratch, overwritten by final

    const long sFF = (long)Ff * Ff;
    const long sSF = (long)Ss * Ff;

    cast_colsum<<<dim3(32, Bb), 256, 0, stream>>>(x, x16, msum_p, msumsq_p);
    meanred<<<Bb, 256, 0, stream>>>(msum_p, msumsq_p, rm, rcov, mbar, mv, scal);

    // sigma + S16, TN-form from x16, triangle + mirror
    gram_tn<<<640, 256, 0, stream>>>(x16, rcov, mbar, mv, scal, sig32, S16);

    // G1: W = sn^2 -> T,U (TRI)
    gemm_bt<6, 128, 64, 4, 8, true><<<640, 256, 0, stream>>>(
        S16, Ff, sFF, S16, Ff, sFF, nullptr, Ff,
        sig32, nullptr, T16, U16, nullptr, scal, Ff, sFF);
    // G2: P2 = 1.5 P1 - 0.5 T*U -> P32a, P16 (TRI)
    gemm_bt<4, 128, 64, 4, 8, true><<<640, 256, 0, stream>>>(
        T16, Ff, sFF, U16, Ff, sFF, nullptr, Ff,
        sig32, P32a, P16, nullptr, nullptr, scal, Ff, sFF);

    // iter 3: fused dual {T=P^2, U=P*sn} (TRI); P3 = 1.5*P32a - 0.5 T*U -> P32b
    gemm_bt<8, 128, 64, 4, 8, true><<<640, 256, 0, stream>>>(
        P16, Ff, sFF, P16, Ff, sFF, S16, Ff,
        nullptr, nullptr, T16, U16, nullptr, nullptr, Ff, sFF);
    gemm_bt<2, 128, 64, 4, 8, true><<<640, 256, 0, stream>>>(
        T16, Ff, sFF, U16, Ff, sFF, nullptr, Ff,
        P32a, P32b, P16, nullptr, nullptr, nullptr, Ff, sFF);
    // iter 4: fused dual (TRI); P4 = 1.5*P32b - 0.5 T*U -> P16 only
    gemm_bt<8, 128, 64, 4, 8, true><<<640, 256, 0, stream>>>(
        P16, Ff, sFF, P16, Ff, sFF, S16, Ff,
        nullptr, nullptr, T16, U16, nullptr, nullptr, Ff, sFF);
    gemm_bt<7, 128, 64, 4, 8, true><<<640, 256, 0, stream>>>(
        T16, Ff, sFF, U16, Ff, sFF, nullptr, Ff,
        P32b, nullptr, P16, nullptr, nullptr, nullptr, Ff, sFF);

    mvecp<<<dim3(Bb, 2), 256, 0, stream>>>(mv, P16, vvec);

    // out = (x@P4 - mv@P4) * tr^{-1/2}
    gemm_bt<3, 128, 128, 16, 4, false><<<2048, 256, 0, stream>>>(
        x16, Ff, sSF, P16, Ff, sFF, nullptr, Ff,
        nullptr, out, nullptr, nullptr, vvec, scal, Ff, sSF);
}